// Round 15
// baseline (288.486 us; speedup 1.0000x reference)
//
#include <hip/hip_runtime.h>
#include <cstdint>
#include <cstddef>

// ---------- types ----------
typedef __bf16 bf16x8 __attribute__((ext_vector_type(8)));
typedef float  f32x4  __attribute__((ext_vector_type(4)));
typedef unsigned short us8 __attribute__((ext_vector_type(8)));
typedef unsigned short us4 __attribute__((ext_vector_type(4)));

__device__ __forceinline__ unsigned short f2bf(float f) {
  union { float f; unsigned u; } v; v.f = f;
  unsigned r = v.u + 0x7FFFu + ((v.u >> 16) & 1u);
  return (unsigned short)(r >> 16);
}
__device__ __forceinline__ float b2f(unsigned short h) {
  union { unsigned u; float f; } v; v.u = ((unsigned)h) << 16;
  return v.f;
}
__device__ __forceinline__ f32x4 mfma16(bf16x8 a, bf16x8 b, f32x4 c) {
  return __builtin_amdgcn_mfma_f32_16x16x32_bf16(a, b, c, 0, 0, 0);
}
// async global->LDS, 16B per lane; lds dest wave-uniform (HW writes base + lane*16)
__device__ __forceinline__ void gl_lds16(const unsigned short* g, unsigned short* l) {
  __builtin_amdgcn_global_load_lds(
      (const __attribute__((address_space(1))) void*)g,
      (__attribute__((address_space(3))) void*)l, 16, 0, 0);
}

// ---------- fused prep: rope tables + biases + pad + counters + 7 weight transposes ----------
// wB1 padded to [2048][2048] (rows 1600..2047 zero) so GEMM1 grid = 512 = 2/CU exact.
__global__ void prep_all_kernel(const float* __restrict__ b_qkv,
                                const float* __restrict__ b_kpos,
                                const float* __restrict__ b_qup,
                                const float* __restrict__ b_qpos,
                                float* __restrict__ bias1,
                                float* __restrict__ bias2q,
                                float* __restrict__ costab,
                                float* __restrict__ sintab,
                                unsigned short* __restrict__ wB1,
                                const float* __restrict__ w_qkv,
                                const float* __restrict__ w_kpos,
                                const float* __restrict__ w_qup,
                                const float* __restrict__ w_qpos,
                                const float* __restrict__ w_kup,
                                const float* __restrict__ w_vup,
                                const float* __restrict__ w_o,
                                unsigned short* __restrict__ wB2q,
                                unsigned short* __restrict__ wB2k,
                                unsigned short* __restrict__ wB2v,
                                unsigned short* __restrict__ wBo,
                                int* __restrict__ counters) {
  __shared__ float tile[32][33];
  int blk = blockIdx.x;
  if (blk < 512) {
    int i = blk * 256 + threadIdx.x;   // covers 131072
    if (i < 65536) {                   // 2048 x 32 rope tables
      int s = i >> 5, f = i & 31;
      float inv = powf(50000.0f, -(float)f / 32.0f);
      float a = (float)s * inv;
      costab[i] = cosf(a);
      sintab[i] = sinf(a);
    }
    if (i < 2048) bias1[i] = (i < 1536) ? b_qkv[i] : (i < 1600 ? b_kpos[i - 1536] : 0.0f);
    if (i < 3072) bias2q[i] = (i < 2048) ? b_qup[i] : b_qpos[i - 2048];
    // zero-pad wB1 rows 1600..2047: 448*2048 = 917504 shorts; 131072 lanes x 7
    for (int jj = 0; jj < 7; ++jj)
      wB1[(size_t)1600 * 2048 + (size_t)jj * 131072 + i] = 0;
    if (i < 64) counters[i] = 0;       // flash steal counter reset
    return;
  }
  const float* in;
  unsigned short* out;
  int ldin, ldo, nx, j;
  if (blk < 3584)      { j = blk - 512;  in = w_qkv;  ldin = 1536; out = wB1;                        ldo = 2048; nx = 48; }
  else if (blk < 3712) { j = blk - 3584; in = w_kpos; ldin = 64;   out = wB1 + (size_t)1536 * 2048;  ldo = 2048; nx = 2;  }
  else if (blk < 4736) { j = blk - 3712; in = w_qup;  ldin = 2048; out = wB2q;                       ldo = 512;  nx = 64; }
  else if (blk < 5248) { j = blk - 4736; in = w_qpos; ldin = 1024; out = wB2q + (size_t)2048 * 512;  ldo = 512;  nx = 32; }
  else if (blk < 6272) { j = blk - 5248; in = w_kup;  ldin = 2048; out = wB2k;                       ldo = 512;  nx = 64; }
  else if (blk < 7296) { j = blk - 6272; in = w_vup;  ldin = 2048; out = wB2v;                       ldo = 512;  nx = 64; }
  else                 { j = blk - 7296; in = w_o;    ldin = 2048; out = wBo;                        ldo = 2048; nx = 64; }
  int c0 = (j % nx) * 32, r0 = (j / nx) * 32;
  int tx = threadIdx.x & 31, ty = threadIdx.x >> 5;
  for (int jj = 0; jj < 4; ++jj)
    tile[ty + jj * 8][tx] = in[(size_t)(r0 + ty + jj * 8) * ldin + c0 + tx];
  __syncthreads();
  for (int jj = 0; jj < 4; ++jj)
    out[(size_t)(c0 + ty + jj * 8) * ldo + r0 + tx] = f2bf(tile[tx][ty + jj * 8]);
}

// ---------- XCD-aware bijective block remap (nwg % 8 == 0 for all our grids) ----------
__device__ __forceinline__ void xcd_decode(int nx, int& bx, int& by) {
  int bid = blockIdx.x, nwg = gridDim.x;
  int cpx = nwg >> 3;
  int wg = (bid & 7) * cpx + (bid >> 3);
  bx = wg % nx;
  by = wg / nx;
}

// ---------- GEMM (bf16 A): 128x128, BK=64, dbuf, counted vmcnt(8), 1D grid ----------
// OUT_MODE: 0 = bf16 row-major, 1 = f32 row-major, 2 = bf16 transposed (vT epilogue).
template <int OUT_MODE>
__global__ __launch_bounds__(256, 2)
void gemm_bt_kernel(const unsigned short* __restrict__ A, int lda,
                    const unsigned short* __restrict__ Bt, int ldb,
                    void* __restrict__ Cout, int ldc,
                    const float* __restrict__ bias, int K, int nx) {
  __shared__ unsigned short smem[32768];   // 2 bufs x (A[128][64] + B[128][64])
  int tid = threadIdx.x;
  int wave = tid >> 6, lane = tid & 63;
  int g = lane >> 4, r = lane & 15;
  int wr = wave >> 1, wc = wave & 1;
  int bx, by;
  xcd_decode(nx, bx, by);
  long brow = (long)by * 128, bcol = (long)bx * 128;

  int srowl = lane >> 3;                        // 0..7 within the 8-row call
  int sw = ((lane & 7) ^ (srowl & 7)) * 8;      // swizzled col offset (shorts)
  const unsigned short* Abase = A + (brow + wave * 32 + srowl) * (long)lda + sw;
  const unsigned short* Bbase = Bt + (bcol + wave * 32 + srowl) * (long)ldb + sw;

  f32x4 acc[4][4];
  for (int mi = 0; mi < 4; ++mi)
    for (int ni = 0; ni < 4; ++ni)
      acc[mi][ni] = f32x4{0.f, 0.f, 0.f, 0.f};

  auto stage = [&](int buf, int k0) {
    unsigned short* ab = smem + buf * 16384;
    unsigned short* bb = ab + 8192;
    for (int c = 0; c < 4; ++c) {
      gl_lds16(Abase + (size_t)c * 8 * lda + k0, ab + (wave * 32 + c * 8) * 64);
      gl_lds16(Bbase + (size_t)c * 8 * ldb + k0, bb + (wave * 32 + c * 8) * 64);
    }
  };

  int rx = (r & 7) << 4;
  int nt = K >> 6;

  stage(0, 0);
  for (int t = 0; t < nt; ++t) {
    if (t + 1 < nt) {
      stage((t + 1) & 1, (t + 1) << 6);
      asm volatile("s_waitcnt vmcnt(8)" ::: "memory");
    } else {
      asm volatile("s_waitcnt vmcnt(0)" ::: "memory");
    }
    __builtin_amdgcn_sched_barrier(0);
    __builtin_amdgcn_s_barrier();
    __builtin_amdgcn_sched_barrier(0);
    const char* Ab = (const char*)(smem + (t & 1) * 16384);
    const char* Bb = Ab + 16384;
    for (int kk = 0; kk < 2; ++kk) {
      bf16x8 af[4], bfv[4];
      for (int mi = 0; mi < 4; ++mi)
        af[mi] = *(const bf16x8*)(Ab + (size_t)(wr * 64 + mi * 16 + r) * 128 +
                                  ((kk * 64 + g * 16) ^ rx));
      for (int ni = 0; ni < 4; ++ni)
        bfv[ni] = *(const bf16x8*)(Bb + (size_t)(wc * 64 + ni * 16 + r) * 128 +
                                   ((kk * 64 + g * 16) ^ rx));
      for (int mi = 0; mi < 4; ++mi)
        for (int ni = 0; ni < 4; ++ni)
          acc[mi][ni] = mfma16(af[mi], bfv[ni], acc[mi][ni]);
    }
    __builtin_amdgcn_sched_barrier(0);
    __builtin_amdgcn_s_barrier();
  }

  if (OUT_MODE == 2) {
    for (int mi = 0; mi < 4; ++mi)
      for (int ni = 0; ni < 4; ++ni) {
        int col = wc * 64 + ni * 16 + r;
        float bv = bias[bcol + col];
        int rowb = wr * 64 + mi * 16 + g * 4;
        for (int i = 0; i < 4; ++i)
          smem[col * 136 + rowb + i] = f2bf(acc[mi][ni][i] + bv);
      }
    __syncthreads();
    int col = tid >> 1, half = tid & 1;
    int bh = (int)(brow >> 11) * 16 + (int)(bcol >> 7);
    unsigned short* outp = (unsigned short*)Cout +
                           ((size_t)bh * 128 + col) * 2048 + (brow & 2047);
    for (int j = 0; j < 8; ++j) {
      int row0 = half * 64 + j * 8;
      *(us8*)(outp + row0) = *(const us8*)&smem[col * 136 + row0];
    }
    return;
  }

  for (int mi = 0; mi < 4; ++mi)
    for (int ni = 0; ni < 4; ++ni) {
      long col = bcol + wc * 64 + ni * 16 + r;
      float bv = bias ? bias[col] : 0.0f;
      long rowb = brow + wr * 64 + mi * 16 + g * 4;
      for (int i = 0; i < 4; ++i) {
        float v = acc[mi][ni][i] + bv;
        if (OUT_MODE == 1)
          ((float*)Cout)[(rowb + i) * (long)ldc + col] = v;
        else
          ((unsigned short*)Cout)[(rowb + i) * (long)ldc + col] = f2bf(v);
      }
    }
}

// ---------- GEMM1: A is fp32 (x), reg-staged with in-register bf16 convert; B bf16 ----------
__global__ __launch_bounds__(256, 2)
void gemm_a32_kernel(const float* __restrict__ A, int lda,
                     const unsigned short* __restrict__ Bt, int ldb,
                     unsigned short* __restrict__ Cout, int ldc,
                     const float* __restrict__ bias, int K, int nx) {
  __shared__ unsigned short smem[32768];   // A bufs [0,16384), B bufs [16384,32768)
  int tid = threadIdx.x;
  int wave = tid >> 6, lane = tid & 63;
  int g = lane >> 4, r = lane & 15;
  int wr = wave >> 1, wc = wave & 1;
  int bx, by;
  xcd_decode(nx, bx, by);
  long brow = (long)by * 128, bcol = (long)bx * 128;

  // A staging: thread covers (row0 + s*16, f4c) for s<8
  int f4c = tid & 15, row0 = tid >> 4;
  int ablk = f4c >> 1, asub = (f4c & 1) * 8;   // LDS 16B-block, byte sub-offset
  const float4* Ag = (const float4*)(A + (brow + row0) * (size_t)lda) + f4c;

  // B staging (as gemm_bt)
  int srowl = lane >> 3;
  int sw = ((lane & 7) ^ (srowl & 7)) * 8;
  const unsigned short* Bbase = Bt + (bcol + wave * 32 + srowl) * (long)ldb + sw;

  f32x4 acc[4][4];
  for (int mi = 0; mi < 4; ++mi)
    for (int ni = 0; ni < 4; ++ni)
      acc[mi][ni] = f32x4{0.f, 0.f, 0.f, 0.f};

  auto stage_b = [&](int buf, int k0) {
    unsigned short* bb = smem + 16384 + buf * 8192;
    for (int c = 0; c < 4; ++c)
      gl_lds16(Bbase + (size_t)c * 8 * ldb + k0, bb + (wave * 32 + c * 8) * 64);
  };

  int rx = (r & 7) << 4;
  int nt = K >> 6;

  float4 areg[8];
#pragma unroll
  for (int s = 0; s < 8; ++s) areg[s] = Ag[(size_t)s * 8192];
  stage_b(0, 0);

  for (int t = 0; t < nt; ++t) {
    // convert A(t) regs -> swizzled ds_write (compiler waits the loads)
    char* alds = (char*)(smem + (t & 1) * 8192);
#pragma unroll
    for (int s = 0; s < 8; ++s) {
      us4 hv;
      hv[0] = f2bf(areg[s].x); hv[1] = f2bf(areg[s].y);
      hv[2] = f2bf(areg[s].z); hv[3] = f2bf(areg[s].w);
      int row = row0 + s * 16;
      *(us4*)(alds + row * 128 + ((ablk ^ (row & 7)) << 4) + asub) = hv;
    }
    asm volatile("s_waitcnt vmcnt(0)" ::: "memory");   // B(t) landed
    asm volatile("s_waitcnt lgkmcnt(0)" ::: "memory"); // A ds_writes committed
    __builtin_amdgcn_sched_barrier(0);
    __builtin_amdgcn_s_barrier();
    __builtin_amdgcn_sched_barrier(0);
    if (t + 1 < nt) {
      int k1 = (t + 1) << 6;
#pragma unroll
      for (int s = 0; s < 8; ++s) areg[s] = Ag[(size_t)s * 8192 + (k1 >> 2)];
      stage_b((t + 1) & 1, k1);
    }
    const char* Ab = (const char*)(smem + (t & 1) * 8192);
    const char* Bb = (const char*)(smem + 16384 + (t & 1) * 8192);
    for (int kk = 0; kk < 2; ++kk) {
      bf16x8 af[4], bfv[4];
      for (int mi = 0; mi < 4; ++mi)
        af[mi] = *(const bf16x8*)(Ab + (size_t)(wr * 64 + mi * 16 + r) * 128 +
                                  ((kk * 64 + g * 16) ^ rx));
      for (int ni = 0; ni < 4; ++ni)
        bfv[ni] = *(const bf16x8*)(Bb + (size_t)(wc * 64 + ni * 16 + r) * 128 +
                                   ((kk * 64 + g * 16) ^ rx));
      for (int mi = 0; mi < 4; ++mi)
        for (int ni = 0; ni < 4; ++ni)
          acc[mi][ni] = mfma16(af[mi], bfv[ni], acc[mi][ni]);
    }
    __builtin_amdgcn_sched_barrier(0);
    __builtin_amdgcn_s_barrier();
  }

  for (int mi = 0; mi < 4; ++mi)
    for (int ni = 0; ni < 4; ++ni) {
      long col = bcol + wc * 64 + ni * 16 + r;
      float bv = bias[col];
      long rowb = brow + wr * 64 + mi * 16 + g * 4;
      for (int i = 0; i < 4; ++i)
        Cout[(rowb + i) * (long)ldc + col] = f2bf(acc[mi][ni][i] + bv);
    }
}

// ---------- rope: posqr[4096][1024] (per-head 64) and poskr[4096][64], vectorized ----------
__global__ void rope_kernel(const unsigned short* __restrict__ tmp_q,
                            const unsigned short* __restrict__ latext,
                            const float* __restrict__ costab,
                            const float* __restrict__ sintab,
                            unsigned short* __restrict__ posqr,
                            unsigned short* __restrict__ poskr) {
  int idx = blockIdx.x * 256 + threadIdx.x;  // 524288 posq + 32768 posk = 557056
  const unsigned short* src;
  unsigned short* dst;
  int s, dp0;
  if (idx < 524288) {
    int rowA = idx >> 7, rem = idx & 127;
    int h = rem >> 3;
    dp0 = (rem & 7) * 8;
    s = rowA & 2047;
    src = tmp_q + (size_t)rowA * 3072 + 2048 + h * 64;
    dst = posqr + (size_t)rowA * 1024 + h * 64 + dp0;
  } else if (idx < 557056) {
    int j = idx - 524288;
    int rowA = j >> 3;
    dp0 = (j & 7) * 8;
    s = rowA & 2047;
    src = latext + (size_t)rowA * 2048 + 1536;
    dst = poskr + (size_t)rowA * 64 + dp0;
  } else {
    return;
  }
  us8 x1 = *(const us8*)(src + dp0);
  us8 x2 = *(const us8*)(src + (dp0 ^ 32));
  int f0 = dp0 & 31;
  const float* cp = costab + s * 32 + f0;
  const float* sp = sintab + s * 32 + f0;
  bool low = dp0 < 32;
  us8 o;
  for (int e = 0; e < 8; ++e) {
    float a = b2f(x1[e]), b = b2f(x2[e]);
    float v = low ? (a * cp[e] - b * sp[e]) : (a * cp[e] + b * sp[e]);
    o[e] = f2bf(v);
  }
  *(us8*)dst = o;
}

// ---------- task decode: 2560 tasks (QBLK=64, <=16 chunks/seg), longest-first ----------
__device__ __forceinline__ void task_decode(int t, int& qt, int& seg, int& bh) {
  if (t < 1024) {
    qt = 31 - (t >> 7); int rem = t & 127; seg = rem >> 5; bh = rem & 31;
  } else if (t < 1792) {
    int t2 = t - 1024; int qi = t2 / 96; int rem = t2 - qi * 96;
    qt = 23 - qi; seg = rem >> 5; bh = rem & 31;
  } else if (t < 2304) {
    int t3 = t - 1792; qt = 15 - (t3 >> 6); int rem = t3 & 63; seg = rem >> 5; bh = rem & 31;
  } else {
    int t4 = t - 2304; qt = 7 - (t4 >> 5); seg = 0; bh = t4 & 31;
  }
}
__device__ __forceinline__ int task_slot(int qt, int seg, int bh) {
  if (qt >= 24) return (31 - qt) * 128 + seg * 32 + bh;
  if (qt >= 16) return 1024 + (23 - qt) * 96 + seg * 32 + bh;
  return 1792 + (15 - qt) * 64 + seg * 32 + bh;
}

// ---------- persistent split-KV causal flash attention, KVBLK=64 ----------
// R11 inner math; 64 KV rows staged per barrier pair (2 sub-chunks computed
// back-to-back) -> barrier count per KV row halves (m233: stage+barrier is the
// dominant 2-phase stall). LDS 46KB -> 3 blocks/CU, grid 768. Plds reuse between
// sub-chunks is same-wave DS (in-order, safe). Segment chunk counts always even.
__global__ __launch_bounds__(256, 2)
void flash_kernel(const unsigned short* __restrict__ tmp_q,
                  const unsigned short* __restrict__ tmp_k,
                  const unsigned short* __restrict__ posqr,
                  const unsigned short* __restrict__ poskr,
                  const unsigned short* __restrict__ vT,
                  unsigned short* __restrict__ ob,
                  unsigned short* __restrict__ Opart,
                  float* __restrict__ mlbuf,
                  int* __restrict__ counter) {
  const int S = 2048;
  int tid = threadIdx.x, wave = tid >> 6, lane = tid & 63;
  int g = lane >> 4, r = lane & 15;
  const float sl2 = 1.44269504f / 13.8564064605510183f;  // log2e / sqrt(192)
  const float DEFER = 96.0f;

  __shared__ unsigned short Klds[64 * 192];   // 64 rows x 384B, blk16 ^= row&7
  __shared__ unsigned short Vlds[128 * 64];   // 128 rows x 128B, blk16 ^= row&7
  __shared__ unsigned short Plds[4][16][40];
  __shared__ int s_tile;
  char* Kb = (char*)Klds;
  char* Vb = (char*)Vlds;
  int rx7 = (r & 7) << 4;

  us8 onesu;
  for (int e = 0; e < 8; ++e) onesu[e] = 0x3F80;
  bf16x8 ones = *(const bf16x8*)&onesu;

  // staging: K nope 64x16 slots (4/thread), K rope 64x8 (2/thread), V 128x8 (4/thread)
  int kn_row[4], kn_seg[4];
  for (int j = 0; j < 4; ++j) {
    int slot = j * 256 + tid;
    kn_row[j] = slot >> 4;
    kn_seg[j] = slot & 15;
  }
  int kr_row[2], kr_seg[2];
  for (int j = 0; j < 2; ++j) {
    int slot = j * 256 + tid;
    kr_row[j] = slot >> 3;
    kr_seg[j] = slot & 7;
  }
  int v_row[4], v_seg[4];
  for (int j = 0; j < 4; ++j) {
    int slot = j * 256 + tid;
    v_row[j] = slot >> 3;
    v_seg[j] = slot & 7;
  }

  for (;;) {
    if (tid == 0) s_tile = atomicAdd(counter, 1);
    __syncthreads();
    int t = s_tile;
    if (t >= 2560) return;
    int qt, seg, bh;
    task_decode(t, qt, seg, bh);
    int b = bh >> 4, h = bh & 15;
    int qbase = qt * 64;
    int cbeg = seg * 16;
    int cend = min(cbeg + 16, 2 * (qt + 1));   // always even count
    size_t rb = (size_t)b * 2048;

    const unsigned short* kpn = tmp_k + rb * 2048 + h * 128;
    const unsigned short* kpr = poskr + rb * 64;
    const unsigned short* vp = vT + (size_t)bh * 128 * S;

    bf16x8 qf[6];
    {
      size_t qrowA = rb + qbase + wave * 16 + r;
      const unsigned short* qn = tmp_q + qrowA * 3072 + h * 128 + g * 8;
      for (int c = 0; c < 4; ++c) qf[c] = *(const bf16x8*)(qn + c * 32);
      const unsigned short* qr_ = posqr + qrowA * 1024 + h * 64 + g * 8;
      qf[4] = *(const bf16x8*)(qr_);
      qf[5] = *(const bf16x8*)(qr_ + 32);
    }

    f32x4 acc[8];
    for (int d = 0; d < 8; ++d) acc[d] = f32x4{0.f, 0.f, 0.f, 0.f};
    f32x4 lacc = {0.f, 0.f, 0.f, 0.f};
    float m_r[4];
    for (int i = 0; i < 4; ++i) m_r[i] = -3.0e38f;

    us8 kreg[4], krope[2], vreg[4];
    {
      int kv0 = cbeg * 32;
      for (int j = 0; j < 4; ++j)
        kreg[j] = *(const us8*)(kpn + (size_t)(kv0 + kn_row[j]) * 2048 + kn_seg[j] * 8);
      for (int j = 0; j < 2; ++j)
        krope[j] = *(const us8*)(kpr + (size_t)(kv0 + kr_row[j]) * 64 + kr_seg[j] * 8);
      for (int j = 0; j < 4; ++j)
        vreg[j] = *(const us8*)(vp + (size_t)v_row[j] * S + kv0 + v_seg[j] * 8);
    }

    for (int ch = cbeg; ch < cend; ch += 2) {
      for (int j = 0; j < 4; ++j)
        *(us8*)(Kb + (size_t)kn_row[j] * 384 +
                ((kn_seg[j] ^ (kn_row[j] & 7)) << 4)) = kreg[j];
      for (int j = 0; j < 2; ++j)
        *(us8*)(Kb + (size_t)kr_row[j] * 384 +
                (((16 + kr_seg[j]) ^ (kr_row[j] & 7)) << 4)) = krope[j];
      for (int j = 0; j < 4; ++j)
        *(us8*)(Vb + (size_t)v_row[j] * 128 +
                ((v_seg[j] ^ (v_row[j] & 7)) << 4)) = vreg[j];
      asm volatile("s_waitcnt lgkmcnt(0)" ::: "memory");
      __builtin_amdgcn_sched_barrier(0);
      __builtin_amdgcn_s_barrier();
      __builtin_amdgcn_sched_barrier(0);
      if (ch + 2 < cend) {
        int kv1 = (ch + 2) * 32;
        for (int j = 0; j < 4; ++j)
          kreg[j] = *(const us8*)(kpn + (size_t)(kv1 + kn_row[j]) * 2048 + kn_seg[j] * 8);
        for (int j = 0; j < 2; ++j)
          krope[j] = *(const us8*)(kpr + (size_t)(kv1 + kr_row[j]) * 64 + kr_seg[j] * 8);
        for (int j = 0; j < 4; ++j)
          vreg[j] = *(const us8*)(vp + (size_t)v_row[j] * S + kv1 + v_seg[j] * 8);
      }

#pragma unroll
      for (int sub = 0; sub < 2; ++sub) {
        int kv0 = (ch + sub) * 32;
        int krow0 = sub * 32;             // K LDS row base for this sub-chunk

        f32x4 sc0 = {0.f, 0.f, 0.f, 0.f}, sc1 = {0.f, 0.f, 0.f, 0.f};
        __builtin_amdgcn_s_setprio(1);
        for (int c = 0; c < 6; ++c) {
          bf16x8 kf0 = *(const bf16x8*)(Kb + (size_t)(krow0 + r) * 384 +
                                        (((c * 4 + g) << 4) ^ rx7));
          sc0 = mfma16(qf[c], kf0, sc0);
        }
        for (int c = 0; c < 6; ++c) {
          bf16x8 kf1 = *(const bf16x8*)(Kb + (size_t)(krow0 + 16 + r) * 384 +
                                        (((c * 4 + g) << 4) ^ rx7));
          sc1 = mfma16(qf[c], kf1, sc1);
        }
        __builtin_amdgcn_s_setprio(0);

        int qi_min = qbase + wave * 16;
        if (kv0 + 31 > qi_min) {
          int kj0 = kv0 + r, kj1 = kv0 + 16 + r;
          int qi0 = qi_min + g * 4;
          for (int i = 0; i < 4; ++i) {
            if (kj0 > qi0 + i) sc0[i] = -1e30f;
            if (kj1 > qi0 + i) sc1[i] = -1e30f;
          }
        }

        float tl[4];
        bool ok = true;
        for (int i = 0; i < 4; ++i) {
          tl[i] = fmaxf(sc0[i], sc1[i]);
          ok = ok && (tl[i] - m_r[i] <= DEFER);
        }
        if (!__all(ok)) {
          for (int i = 0; i < 4; ++i) {
            float tm = tl[i];
            for (int off = 1; off < 16; off <<= 1) tm = fmaxf(tm, __shfl_xor(tm, off, 64));
            float mnew = fmaxf(m_r[i], tm);
            float corr = exp2f((m_r[i] - mnew) * sl2);
            lacc[i] *= corr;
            for (int d = 0; d < 8; ++d) acc[d][i] *= corr;
            m_r[i] = mnew;
          }
        }
        float p0[4], p1[4];
        for (int i = 0; i < 4; ++i) {
          p0[i] = exp2f((sc0[i] - m_r[i]) * sl2);
          p1[i] = exp2f((sc1[i] - m_r[i]) * sl2);
        }

        for (int i = 0; i < 4; ++i) {
          Plds[wave][g * 4 + i][r] = f2bf(p0[i]);
          Plds[wave][g * 4 + i][16 + r] = f2bf(p1[i]);
        }
        bf16x8 pa = *(const bf16x8*)&Plds[wave][r][g * 8];
        __builtin_amdgcn_s_setprio(1);
        lacc = mfma16(pa, ones, lacc);
        for (int dt = 0; dt < 8; ++dt) {
          bf16x8 vf = *(const bf16x8*)(Vb + (size_t)(dt * 16 + r) * 128 +
                                       (((sub * 4 + g) << 4) ^ rx7));
          acc[dt] = mfma16(pa, vf, acc[dt]);
        }
        __builtin_amdgcn_s_setprio(0);
      }
      __builtin_amdgcn_sched_barrier(0);
      __builtin_amdgcn_s_barrier();   // all reads done -> next pair may overwrite
    }

    if (qt <= 7) {
      for (int i = 0; i < 4; ++i) {
        float inv = 1.0f / lacc[i];
        int row = qbase + wave * 16 + g * 4 + i;
        size_t base = (rb + row) * 2048 + h * 128;
        for (int dt = 0; dt < 8; ++dt)
          ob[base + dt * 16 + r] = f2bf(acc[dt][i] * inv);
      }
    } else {
      unsigned short* op = Opart + (size_t)t * 8192;
      for (int i = 0; i < 4; ++i) {
        int row = wave * 16 + g * 4 + i;
        for (int dt = 0; dt < 8; ++dt)
          op[row * 128 + dt * 16 + r] = f2bf(acc[dt][i]);
        if (r == 0) {
          mlbuf[(size_t)t * 128 + row * 2]     = m_r[i];
          mlbuf[(size_t)t * 128 + row * 2 + 1] = lacc[i];
        }
      }
    }
  }
}

// ---------- merge partials (qt>=8) -> attn bf16 [B*S, 2048] ----------
__global__ void merge_kernel(const unsigned short* __restrict__ Opart,
                             const float* __restrict__ mlbuf,
                             unsigned short* __restrict__ ob) {
  int qt = 8 + (blockIdx.x >> 5), bh = blockIdx.x & 31;
  int b = bh >> 4, h = bh & 15;
  int tid = threadIdx.x;
  int row = tid >> 2, c0 = (tid & 3) * 32;
  const float sl2 = 1.44269504f / 13.8564064605510183f;
  int ns = (qt >= 24) ? 4 : (qt >= 16 ? 3 : 2);

  size_t slot[4];
  float m[4], l[4], w[4];
  float M = -3.0e38f;
#pragma unroll
  for (int j = 0; j < 4; ++j) {
    if (j < ns) {
      slot[j] = task_slot(qt, j, bh);
      m[j] = mlbuf[slot[j] * 128 + row * 2];
      l[j] = mlbuf[slot[j] * 128 + row * 2 + 1];
      M = fmaxf(M, m[j]);
    }
  }
  float L = 0.f;
#pragma unroll
  for (int j = 0; j < 4; ++j)
    if (j < ns) { w[j] = exp2f((m[j] - M) * sl2); L += w[j] * l[j]; }
  float invL = 1.f / L;
#pragma unroll
  for (int j = 0; j < 4; ++j) if (j < ns) w[j] *= invL;

  float o[32];
#pragma unroll
  for (int e = 0; e < 32; ++e) o[e] = 0.f;
#pragma unroll
  for (int j = 0; j < 4; ++j) {
    if (j < ns) {
      const unsigned short* pp = Opart + slot[j] * 8192 + row * 128 + c0;
      for (int blk = 0; blk < 4; ++blk) {
        us8 v = *(const us8*)(pp + blk * 8);
        for (int e = 0; e < 8; ++e) o[blk * 8 + e] += w[j] * b2f(v[e]);
      }
    }
  }
  size_t obase = ((size_t)b * 2048 + qt * 64 + row) * 2048 + h * 128 + c0;
  for (int blk = 0; blk < 4; ++blk) {
    us8 st;
    for (int e = 0; e < 8; ++e) st[e] = f2bf(o[blk * 8 + e]);
    *(us8*)(ob + obase + blk * 8) = st;
  }
}

// ---------- launcher ----------
extern "C" void kernel_launch(void* const* d_in, const int* in_sizes, int n_in,
                              void* d_out, int out_size, void* d_ws, size_t ws_size,
                              hipStream_t stream) {
  const float* x      = (const float*)d_in[0];
  const float* w_qkv  = (const float*)d_in[1];
  const float* b_qkv  = (const float*)d_in[2];
  const float* w_qup  = (const float*)d_in[3];
  const float* b_qup  = (const float*)d_in[4];
  const float* w_kup  = (const float*)d_in[5];
  const float* b_kup  = (const float*)d_in[6];
  const float* w_vup  = (const float*)d_in[7];
  const float* b_vup  = (const float*)d_in[8];
  const float* w_qpos = (const float*)d_in[9];
  const float* b_qpos = (const float*)d_in[10];
  const float* w_kpos = (const float*)d_in[11];
  const float* b_kpos = (const float*)d_in[12];
  const float* w_o    = (const float*)d_in[13];
  const float* b_o    = (const float*)d_in[14];
  (void)in_sizes; (void)n_in; (void)out_size; (void)ws_size;

  char* ws = (char*)d_ws;
  size_t off = 0;
  auto alloc = [&](size_t bytes) -> char* {
    char* p = ws + off;
    off += (bytes + 255) & ~(size_t)255;
    return p;
  };

  unsigned short* wB1    = (unsigned short*)alloc(8388608);   // [2048,2048] (rows 1600+ zero)
  unsigned short* wB2q   = (unsigned short*)alloc(3145728);   // [3072,512]
  unsigned short* wB2k   = (unsigned short*)alloc(2097152);   // [2048,512]
  unsigned short* wB2v   = (unsigned short*)alloc(2097152);   // [2048,512]
  unsigned short* wBo    = (unsigned short*)alloc(8388608);   // [2048,2048]
  float*          bias1  = (float*)alloc(2048 * 4);
  float*          bias2q = (float*)alloc(3072 * 4);
  float*          costab = (float*)alloc(262144);
  float*          sintab = (float*)alloc(262144);
  unsigned short* latext = (unsigned short*)alloc(16777216);  // [4096,2048]
  unsigned short* tmp_q  = (unsigned short*)alloc(25165824);  // [4096,3072]
  unsigned short* tmp_k  = (unsigned short*)alloc(16777216);  // [4096,2048]
  unsigned short* vTbuf  = (unsigned short*)alloc(16777216);  // [32,128,2048]
  unsigned short* posqr  = (unsigned short*)alloc(8388608);   // [4096,1024]
  unsigned short* poskr  = (unsigned short*)alloc(524288);    // [4096,64]
  unsigned short* Opart  = (unsigned short*)alloc(41943040);  // [2560][64][128] bf16
  float*          mlbuf  = (float*)alloc(1310720);            // [2560][64][2]
  int*            counter= (int*)alloc(256);
  unsigned short* attnb  = (unsigned short*)alloc(16777216);  // [4096,2048] bf16

  // 1. fused prep: rope tables, biases, pad, counter reset, 7 weight transposes
  prep_all_kernel<<<11392, 256, 0, stream>>>(b_qkv, b_kpos, b_qup, b_qpos,
                                             bias1, bias2q, costab, sintab, wB1,
                                             w_qkv, w_kpos, w_qup, w_qpos, w_kup,
                                             w_vup, w_o, wB2q, wB2k, wB2v, wBo,
                                             counter);
  // 2. GEMM1 (fp32 A direct): latext[4096,2048] = x @ wB1^T + bias1 (cols 1664+ dead)
  gemm_a32_kernel<<<512, 256, 0, stream>>>(x, 2048, wB1, 2048,
                                           latext, 2048, bias1, 2048, 16);
  // 3. up-projections (K=512); v-up writes vT directly
  gemm_bt_kernel<0><<<768, 256, 0, stream>>>(latext, 2048, wB2q, 512,
                                             tmp_q, 3072, bias2q, 512, 24);
  gemm_bt_kernel<0><<<512, 256, 0, stream>>>(latext + 512, 2048, wB2k, 512,
                                             tmp_k, 2048, b_kup, 512, 16);
  gemm_bt_kernel<2><<<512, 256, 0, stream>>>(latext + 1024, 2048, wB2v, 512,
                                             vTbuf, 2048, b_vup, 512, 16);
  // 4. rope
  rope_kernel<<<2176, 256, 0, stream>>>(tmp_q, latext, costab, sintab, posqr, poskr);
  // 5. flash attention (KVBLK=64, grid 768 = 3 blocks/CU LDS cap)
  flash_kernel<<<768, 256, 0, stream>>>(tmp_q, tmp_k, posqr, poskr, vTbuf,
                                        attnb, Opart, mlbuf, counter);
  // 6. merge partials (qt>=8) -> attnb
  merge_kernel<<<768, 256, 0, stream>>>(Opart, mlbuf, attnb);
  // 7. output projection (fp32 out + b_o)
  gemm_bt_kernel<1><<<512, 256, 0, stream>>>(attnb, 2048, wBo, 2048,
                                             d_out, 2048, b_o, 2048, 16);
}

// Round 16
// 280.407 us; speedup vs baseline: 1.0288x; 1.0288x over previous
//
#include <hip/hip_runtime.h>
#include <cstdint>
#include <cstddef>

// ---------- types ----------
typedef __bf16 bf16x8 __attribute__((ext_vector_type(8)));
typedef float  f32x4  __attribute__((ext_vector_type(4)));
typedef unsigned short us8 __attribute__((ext_vector_type(8)));
typedef unsigned short us4 __attribute__((ext_vector_type(4)));

__device__ __forceinline__ unsigned short f2bf(float f) {
  union { float f; unsigned u; } v; v.f = f;
  unsigned r = v.u + 0x7FFFu + ((v.u >> 16) & 1u);
  return (unsigned short)(r >> 16);
}
__device__ __forceinline__ float b2f(unsigned short h) {
  union { unsigned u; float f; } v; v.u = ((unsigned)h) << 16;
  return v.f;
}
__device__ __forceinline__ f32x4 mfma16(bf16x8 a, bf16x8 b, f32x4 c) {
  return __builtin_amdgcn_mfma_f32_16x16x32_bf16(a, b, c, 0, 0, 0);
}
// async global->LDS, 16B per lane; lds dest wave-uniform (HW writes base + lane*16)
__device__ __forceinline__ void gl_lds16(const unsigned short* g, unsigned short* l) {
  __builtin_amdgcn_global_load_lds(
      (const __attribute__((address_space(1))) void*)g,
      (__attribute__((address_space(3))) void*)l, 16, 0, 0);
}

// ---------- fused prep: rope tables + biases + pad + counters + 7 weight transposes ----------
// wB1 padded to [2048][2048] (rows 1600..2047 zero) so GEMM1 grid = 512 = 2/CU exact.
__global__ void prep_all_kernel(const float* __restrict__ b_qkv,
                                const float* __restrict__ b_kpos,
                                const float* __restrict__ b_qup,
                                const float* __restrict__ b_qpos,
                                float* __restrict__ bias1,
                                float* __restrict__ bias2q,
                                float* __restrict__ costab,
                                float* __restrict__ sintab,
                                unsigned short* __restrict__ wB1,
                                const float* __restrict__ w_qkv,
                                const float* __restrict__ w_kpos,
                                const float* __restrict__ w_qup,
                                const float* __restrict__ w_qpos,
                                const float* __restrict__ w_kup,
                                const float* __restrict__ w_vup,
                                const float* __restrict__ w_o,
                                unsigned short* __restrict__ wB2q,
                                unsigned short* __restrict__ wB2k,
                                unsigned short* __restrict__ wB2v,
                                unsigned short* __restrict__ wBo,
                                int* __restrict__ counters) {
  __shared__ float tile[32][33];
  int blk = blockIdx.x;
  if (blk < 512) {
    int i = blk * 256 + threadIdx.x;   // covers 131072
    if (i < 65536) {                   // 2048 x 32 rope tables
      int s = i >> 5, f = i & 31;
      float inv = powf(50000.0f, -(float)f / 32.0f);
      float a = (float)s * inv;
      costab[i] = cosf(a);
      sintab[i] = sinf(a);
    }
    if (i < 2048) bias1[i] = (i < 1536) ? b_qkv[i] : (i < 1600 ? b_kpos[i - 1536] : 0.0f);
    if (i < 3072) bias2q[i] = (i < 2048) ? b_qup[i] : b_qpos[i - 2048];
    // zero-pad wB1 rows 1600..2047: 448*2048 = 917504 shorts; 131072 lanes x 7
    for (int jj = 0; jj < 7; ++jj)
      wB1[(size_t)1600 * 2048 + (size_t)jj * 131072 + i] = 0;
    if (i < 64) counters[i] = 0;       // flash steal counter reset
    return;
  }
  const float* in;
  unsigned short* out;
  int ldin, ldo, nx, j;
  if (blk < 3584)      { j = blk - 512;  in = w_qkv;  ldin = 1536; out = wB1;                        ldo = 2048; nx = 48; }
  else if (blk < 3712) { j = blk - 3584; in = w_kpos; ldin = 64;   out = wB1 + (size_t)1536 * 2048;  ldo = 2048; nx = 2;  }
  else if (blk < 4736) { j = blk - 3712; in = w_qup;  ldin = 2048; out = wB2q;                       ldo = 512;  nx = 64; }
  else if (blk < 5248) { j = blk - 4736; in = w_qpos; ldin = 1024; out = wB2q + (size_t)2048 * 512;  ldo = 512;  nx = 32; }
  else if (blk < 6272) { j = blk - 5248; in = w_kup;  ldin = 2048; out = wB2k;                       ldo = 512;  nx = 64; }
  else if (blk < 7296) { j = blk - 6272; in = w_vup;  ldin = 2048; out = wB2v;                       ldo = 512;  nx = 64; }
  else                 { j = blk - 7296; in = w_o;    ldin = 2048; out = wBo;                        ldo = 2048; nx = 64; }
  int c0 = (j % nx) * 32, r0 = (j / nx) * 32;
  int tx = threadIdx.x & 31, ty = threadIdx.x >> 5;
  for (int jj = 0; jj < 4; ++jj)
    tile[ty + jj * 8][tx] = in[(size_t)(r0 + ty + jj * 8) * ldin + c0 + tx];
  __syncthreads();
  for (int jj = 0; jj < 4; ++jj)
    out[(size_t)(c0 + ty + jj * 8) * ldo + r0 + tx] = f2bf(tile[tx][ty + jj * 8]);
}

// ---------- XCD-aware bijective block remap (nwg % 8 == 0 for all our grids) ----------
__device__ __forceinline__ void xcd_decode(int nx, int& bx, int& by) {
  int bid = blockIdx.x, nwg = gridDim.x;
  int cpx = nwg >> 3;
  int wg = (bid & 7) * cpx + (bid >> 3);
  bx = wg % nx;
  by = wg / nx;
}

// ---------- GEMM (bf16 A): 128x128, BK=64, dbuf, counted vmcnt(8), 1D grid ----------
// OUT_MODE: 0 = bf16 row-major, 1 = f32 row-major, 2 = bf16 transposed (vT epilogue).
template <int OUT_MODE>
__global__ __launch_bounds__(256, 2)
void gemm_bt_kernel(const unsigned short* __restrict__ A, int lda,
                    const unsigned short* __restrict__ Bt, int ldb,
                    void* __restrict__ Cout, int ldc,
                    const float* __restrict__ bias, int K, int nx) {
  __shared__ unsigned short smem[32768];   // 2 bufs x (A[128][64] + B[128][64])
  int tid = threadIdx.x;
  int wave = tid >> 6, lane = tid & 63;
  int g = lane >> 4, r = lane & 15;
  int wr = wave >> 1, wc = wave & 1;
  int bx, by;
  xcd_decode(nx, bx, by);
  long brow = (long)by * 128, bcol = (long)bx * 128;

  int srowl = lane >> 3;                        // 0..7 within the 8-row call
  int sw = ((lane & 7) ^ (srowl & 7)) * 8;      // swizzled col offset (shorts)
  const unsigned short* Abase = A + (brow + wave * 32 + srowl) * (long)lda + sw;
  const unsigned short* Bbase = Bt + (bcol + wave * 32 + srowl) * (long)ldb + sw;

  f32x4 acc[4][4];
  for (int mi = 0; mi < 4; ++mi)
    for (int ni = 0; ni < 4; ++ni)
      acc[mi][ni] = f32x4{0.f, 0.f, 0.f, 0.f};

  auto stage = [&](int buf, int k0) {
    unsigned short* ab = smem + buf * 16384;
    unsigned short* bb = ab + 8192;
    for (int c = 0; c < 4; ++c) {
      gl_lds16(Abase + (size_t)c * 8 * lda + k0, ab + (wave * 32 + c * 8) * 64);
      gl_lds16(Bbase + (size_t)c * 8 * ldb + k0, bb + (wave * 32 + c * 8) * 64);
    }
  };

  int rx = (r & 7) << 4;
  int nt = K >> 6;

  stage(0, 0);
  for (int t = 0; t < nt; ++t) {
    if (t + 1 < nt) {
      stage((t + 1) & 1, (t + 1) << 6);
      asm volatile("s_waitcnt vmcnt(8)" ::: "memory");
    } else {
      asm volatile("s_waitcnt vmcnt(0)" ::: "memory");
    }
    __builtin_amdgcn_sched_barrier(0);
    __builtin_amdgcn_s_barrier();
    __builtin_amdgcn_sched_barrier(0);
    const char* Ab = (const char*)(smem + (t & 1) * 16384);
    const char* Bb = Ab + 16384;
    for (int kk = 0; kk < 2; ++kk) {
      bf16x8 af[4], bfv[4];
      for (int mi = 0; mi < 4; ++mi)
        af[mi] = *(const bf16x8*)(Ab + (size_t)(wr * 64 + mi * 16 + r) * 128 +
                                  ((kk * 64 + g * 16) ^ rx));
      for (int ni = 0; ni < 4; ++ni)
        bfv[ni] = *(const bf16x8*)(Bb + (size_t)(wc * 64 + ni * 16 + r) * 128 +
                                   ((kk * 64 + g * 16) ^ rx));
      for (int mi = 0; mi < 4; ++mi)
        for (int ni = 0; ni < 4; ++ni)
          acc[mi][ni] = mfma16(af[mi], bfv[ni], acc[mi][ni]);
    }
    __builtin_amdgcn_sched_barrier(0);
    __builtin_amdgcn_s_barrier();
  }

  if (OUT_MODE == 2) {
    for (int mi = 0; mi < 4; ++mi)
      for (int ni = 0; ni < 4; ++ni) {
        int col = wc * 64 + ni * 16 + r;
        float bv = bias[bcol + col];
        int rowb = wr * 64 + mi * 16 + g * 4;
        for (int i = 0; i < 4; ++i)
          smem[col * 136 + rowb + i] = f2bf(acc[mi][ni][i] + bv);
      }
    __syncthreads();
    int col = tid >> 1, half = tid & 1;
    int bh = (int)(brow >> 11) * 16 + (int)(bcol >> 7);
    unsigned short* outp = (unsigned short*)Cout +
                           ((size_t)bh * 128 + col) * 2048 + (brow & 2047);
    for (int j = 0; j < 8; ++j) {
      int row0 = half * 64 + j * 8;
      *(us8*)(outp + row0) = *(const us8*)&smem[col * 136 + row0];
    }
    return;
  }

  for (int mi = 0; mi < 4; ++mi)
    for (int ni = 0; ni < 4; ++ni) {
      long col = bcol + wc * 64 + ni * 16 + r;
      float bv = bias ? bias[col] : 0.0f;
      long rowb = brow + wr * 64 + mi * 16 + g * 4;
      for (int i = 0; i < 4; ++i) {
        float v = acc[mi][ni][i] + bv;
        if (OUT_MODE == 1)
          ((float*)Cout)[(rowb + i) * (long)ldc + col] = v;
        else
          ((unsigned short*)Cout)[(rowb + i) * (long)ldc + col] = f2bf(v);
      }
    }
}

// ---------- GEMM1: A is fp32 (x), reg-staged with in-register bf16 convert; B bf16 ----------
__global__ __launch_bounds__(256, 2)
void gemm_a32_kernel(const float* __restrict__ A, int lda,
                     const unsigned short* __restrict__ Bt, int ldb,
                     unsigned short* __restrict__ Cout, int ldc,
                     const float* __restrict__ bias, int K, int nx) {
  __shared__ unsigned short smem[32768];   // A bufs [0,16384), B bufs [16384,32768)
  int tid = threadIdx.x;
  int wave = tid >> 6, lane = tid & 63;
  int g = lane >> 4, r = lane & 15;
  int wr = wave >> 1, wc = wave & 1;
  int bx, by;
  xcd_decode(nx, bx, by);
  long brow = (long)by * 128, bcol = (long)bx * 128;

  // A staging: thread covers (row0 + s*16, f4c) for s<8
  int f4c = tid & 15, row0 = tid >> 4;
  int ablk = f4c >> 1, asub = (f4c & 1) * 8;   // LDS 16B-block, byte sub-offset
  const float4* Ag = (const float4*)(A + (brow + row0) * (size_t)lda) + f4c;

  // B staging (as gemm_bt)
  int srowl = lane >> 3;
  int sw = ((lane & 7) ^ (srowl & 7)) * 8;
  const unsigned short* Bbase = Bt + (bcol + wave * 32 + srowl) * (long)ldb + sw;

  f32x4 acc[4][4];
  for (int mi = 0; mi < 4; ++mi)
    for (int ni = 0; ni < 4; ++ni)
      acc[mi][ni] = f32x4{0.f, 0.f, 0.f, 0.f};

  auto stage_b = [&](int buf, int k0) {
    unsigned short* bb = smem + 16384 + buf * 8192;
    for (int c = 0; c < 4; ++c)
      gl_lds16(Bbase + (size_t)c * 8 * ldb + k0, bb + (wave * 32 + c * 8) * 64);
  };

  int rx = (r & 7) << 4;
  int nt = K >> 6;

  float4 areg[8];
#pragma unroll
  for (int s = 0; s < 8; ++s) areg[s] = Ag[(size_t)s * 8192];
  stage_b(0, 0);

  for (int t = 0; t < nt; ++t) {
    // convert A(t) regs -> swizzled ds_write (compiler waits the loads)
    char* alds = (char*)(smem + (t & 1) * 8192);
#pragma unroll
    for (int s = 0; s < 8; ++s) {
      us4 hv;
      hv[0] = f2bf(areg[s].x); hv[1] = f2bf(areg[s].y);
      hv[2] = f2bf(areg[s].z); hv[3] = f2bf(areg[s].w);
      int row = row0 + s * 16;
      *(us4*)(alds + row * 128 + ((ablk ^ (row & 7)) << 4) + asub) = hv;
    }
    asm volatile("s_waitcnt vmcnt(0)" ::: "memory");   // B(t) landed
    asm volatile("s_waitcnt lgkmcnt(0)" ::: "memory"); // A ds_writes committed
    __builtin_amdgcn_sched_barrier(0);
    __builtin_amdgcn_s_barrier();
    __builtin_amdgcn_sched_barrier(0);
    if (t + 1 < nt) {
      int k1 = (t + 1) << 6;
#pragma unroll
      for (int s = 0; s < 8; ++s) areg[s] = Ag[(size_t)s * 8192 + (k1 >> 2)];
      stage_b((t + 1) & 1, k1);
    }
    const char* Ab = (const char*)(smem + (t & 1) * 8192);
    const char* Bb = (const char*)(smem + 16384 + (t & 1) * 8192);
    for (int kk = 0; kk < 2; ++kk) {
      bf16x8 af[4], bfv[4];
      for (int mi = 0; mi < 4; ++mi)
        af[mi] = *(const bf16x8*)(Ab + (size_t)(wr * 64 + mi * 16 + r) * 128 +
                                  ((kk * 64 + g * 16) ^ rx));
      for (int ni = 0; ni < 4; ++ni)
        bfv[ni] = *(const bf16x8*)(Bb + (size_t)(wc * 64 + ni * 16 + r) * 128 +
                                   ((kk * 64 + g * 16) ^ rx));
      for (int mi = 0; mi < 4; ++mi)
        for (int ni = 0; ni < 4; ++ni)
          acc[mi][ni] = mfma16(af[mi], bfv[ni], acc[mi][ni]);
    }
    __builtin_amdgcn_sched_barrier(0);
    __builtin_amdgcn_s_barrier();
  }

  for (int mi = 0; mi < 4; ++mi)
    for (int ni = 0; ni < 4; ++ni) {
      long col = bcol + wc * 64 + ni * 16 + r;
      float bv = bias[col];
      long rowb = brow + wr * 64 + mi * 16 + g * 4;
      for (int i = 0; i < 4; ++i)
        Cout[(rowb + i) * (long)ldc + col] = f2bf(acc[mi][ni][i] + bv);
    }
}

// ---------- rope: posqr[4096][1024] (per-head 64) and poskr[4096][64], vectorized ----------
__global__ void rope_kernel(const unsigned short* __restrict__ tmp_q,
                            const unsigned short* __restrict__ latext,
                            const float* __restrict__ costab,
                            const float* __restrict__ sintab,
                            unsigned short* __restrict__ posqr,
                            unsigned short* __restrict__ poskr) {
  int idx = blockIdx.x * 256 + threadIdx.x;  // 524288 posq + 32768 posk = 557056
  const unsigned short* src;
  unsigned short* dst;
  int s, dp0;
  if (idx < 524288) {
    int rowA = idx >> 7, rem = idx & 127;
    int h = rem >> 3;
    dp0 = (rem & 7) * 8;
    s = rowA & 2047;
    src = tmp_q + (size_t)rowA * 3072 + 2048 + h * 64;
    dst = posqr + (size_t)rowA * 1024 + h * 64 + dp0;
  } else if (idx < 557056) {
    int j = idx - 524288;
    int rowA = j >> 3;
    dp0 = (j & 7) * 8;
    s = rowA & 2047;
    src = latext + (size_t)rowA * 2048 + 1536;
    dst = poskr + (size_t)rowA * 64 + dp0;
  } else {
    return;
  }
  us8 x1 = *(const us8*)(src + dp0);
  us8 x2 = *(const us8*)(src + (dp0 ^ 32));
  int f0 = dp0 & 31;
  const float* cp = costab + s * 32 + f0;
  const float* sp = sintab + s * 32 + f0;
  bool low = dp0 < 32;
  us8 o;
  for (int e = 0; e < 8; ++e) {
    float a = b2f(x1[e]), b = b2f(x2[e]);
    float v = low ? (a * cp[e] - b * sp[e]) : (a * cp[e] + b * sp[e]);
    o[e] = f2bf(v);
  }
  *(us8*)dst = o;
}

// ---------- task decode: 2560 tasks (QBLK=64, <=16 chunks/seg), longest-first ----------
__device__ __forceinline__ void task_decode(int t, int& qt, int& seg, int& bh) {
  if (t < 1024) {
    qt = 31 - (t >> 7); int rem = t & 127; seg = rem >> 5; bh = rem & 31;
  } else if (t < 1792) {
    int t2 = t - 1024; int qi = t2 / 96; int rem = t2 - qi * 96;
    qt = 23 - qi; seg = rem >> 5; bh = rem & 31;
  } else if (t < 2304) {
    int t3 = t - 1792; qt = 15 - (t3 >> 6); int rem = t3 & 63; seg = rem >> 5; bh = rem & 31;
  } else {
    int t4 = t - 2304; qt = 7 - (t4 >> 5); seg = 0; bh = t4 & 31;
  }
}
__device__ __forceinline__ int task_slot(int qt, int seg, int bh) {
  if (qt >= 24) return (31 - qt) * 128 + seg * 32 + bh;
  if (qt >= 16) return 1024 + (23 - qt) * 96 + seg * 32 + bh;
  return 1792 + (15 - qt) * 64 + seg * 32 + bh;
}

// ---------- persistent split-KV causal flash attention (R14 structure) ----------
// KVBLK=32, 4 waves, grid 1280 (5 blocks/CU), raw barriers, ones-MFMA row-sum,
// T13 defer-max, wave-uniform mask skip. V LDS re-laid to [64 rows][128B] with
// blk16 ^= d&7 (the R15-measured conflict-free geometry: SQ_LDS_BANK_CONFLICT
// 4.87M -> 0.54M came from V's old 64B-row/2-bit-swizzle layout).
__global__ __launch_bounds__(256, 2)
void flash_kernel(const unsigned short* __restrict__ tmp_q,
                  const unsigned short* __restrict__ tmp_k,
                  const unsigned short* __restrict__ posqr,
                  const unsigned short* __restrict__ poskr,
                  const unsigned short* __restrict__ vT,
                  unsigned short* __restrict__ ob,
                  unsigned short* __restrict__ Opart,
                  float* __restrict__ mlbuf,
                  int* __restrict__ counter) {
  const int S = 2048;
  int tid = threadIdx.x, wave = tid >> 6, lane = tid & 63;
  int g = lane >> 4, r = lane & 15;
  const float sl2 = 1.44269504f / 13.8564064605510183f;  // log2e / sqrt(192)
  const float DEFER = 96.0f;

  __shared__ unsigned short Klds[32 * 192];   // 32 rows x 384B, blk16 ^= row&7
  __shared__ unsigned short Vlds[64 * 64];    // 64 rows x 128B: d-rows d,(d+64); blk ^= d&7
  __shared__ unsigned short Plds[4][16][40];
  __shared__ int s_tile;
  char* Kb = (char*)Klds;
  char* Vb = (char*)Vlds;
  int rx7 = (r & 7) << 4;

  us8 onesu;
  for (int e = 0; e < 8; ++e) onesu[e] = 0x3F80;
  bf16x8 ones = *(const bf16x8*)&onesu;

  int kn_row[2], kn_seg[2];
  for (int j = 0; j < 2; ++j) {
    int slot = j * 256 + tid;
    kn_row[j] = slot >> 4;
    kn_seg[j] = slot & 15;
  }
  int kr_row = tid >> 3, kr_seg = tid & 7;
  int v_row[2], v_seg[2];
  for (int j = 0; j < 2; ++j) {
    int slot = j * 256 + tid;
    v_row[j] = slot >> 2;      // global d-row 0..127
    v_seg[j] = slot & 3;       // 16B chunk within staged 32 shorts
  }

  for (;;) {
    if (tid == 0) s_tile = atomicAdd(counter, 1);
    __syncthreads();
    int t = s_tile;
    if (t >= 2560) return;
    int qt, seg, bh;
    task_decode(t, qt, seg, bh);
    int b = bh >> 4, h = bh & 15;
    int qbase = qt * 64;
    int cbeg = seg * 16;
    int cend = min(cbeg + 16, 2 * (qt + 1));
    size_t rb = (size_t)b * 2048;

    const unsigned short* kpn = tmp_k + rb * 2048 + h * 128;
    const unsigned short* kpr = poskr + rb * 64;
    const unsigned short* vp = vT + (size_t)bh * 128 * S;

    bf16x8 qf[6];
    {
      size_t qrowA = rb + qbase + wave * 16 + r;
      const unsigned short* qn = tmp_q + qrowA * 3072 + h * 128 + g * 8;
      for (int c = 0; c < 4; ++c) qf[c] = *(const bf16x8*)(qn + c * 32);
      const unsigned short* qr_ = posqr + qrowA * 1024 + h * 64 + g * 8;
      qf[4] = *(const bf16x8*)(qr_);
      qf[5] = *(const bf16x8*)(qr_ + 32);
    }

    f32x4 acc[8];
    for (int d = 0; d < 8; ++d) acc[d] = f32x4{0.f, 0.f, 0.f, 0.f};
    f32x4 lacc = {0.f, 0.f, 0.f, 0.f};
    float m_r[4];
    for (int i = 0; i < 4; ++i) m_r[i] = -3.0e38f;

    us8 kreg[2], krope, vreg[2];
    {
      int kv0 = cbeg * 32;
      for (int j = 0; j < 2; ++j)
        kreg[j] = *(const us8*)(kpn + (size_t)(kv0 + kn_row[j]) * 2048 + kn_seg[j] * 8);
      krope = *(const us8*)(kpr + (size_t)(kv0 + kr_row) * 64 + kr_seg * 8);
      for (int j = 0; j < 2; ++j)
        vreg[j] = *(const us8*)(vp + (size_t)v_row[j] * S + kv0 + v_seg[j] * 8);
    }

    for (int ch = cbeg; ch < cend; ++ch) {
      for (int j = 0; j < 2; ++j)
        *(us8*)(Kb + (size_t)kn_row[j] * 384 +
                ((kn_seg[j] ^ (kn_row[j] & 7)) << 4)) = kreg[j];
      *(us8*)(Kb + (size_t)kr_row * 384 +
              (((16 + kr_seg) ^ (kr_row & 7)) << 4)) = krope;
      for (int j = 0; j < 2; ++j) {
        int d = v_row[j];
        *(us8*)(Vb + (size_t)(d & 63) * 128 +
                ((((d >> 6) * 4 + v_seg[j]) ^ (d & 7)) << 4)) = vreg[j];
      }
      asm volatile("s_waitcnt lgkmcnt(0)" ::: "memory");
      __builtin_amdgcn_sched_barrier(0);
      __builtin_amdgcn_s_barrier();
      __builtin_amdgcn_sched_barrier(0);
      if (ch + 1 < cend) {
        int kv1 = (ch + 1) * 32;
        for (int j = 0; j < 2; ++j)
          kreg[j] = *(const us8*)(kpn + (size_t)(kv1 + kn_row[j]) * 2048 + kn_seg[j] * 8);
        krope = *(const us8*)(kpr + (size_t)(kv1 + kr_row) * 64 + kr_seg * 8);
        for (int j = 0; j < 2; ++j)
          vreg[j] = *(const us8*)(vp + (size_t)v_row[j] * S + kv1 + v_seg[j] * 8);
      }
      int kv0 = ch * 32;

      f32x4 sc0 = {0.f, 0.f, 0.f, 0.f}, sc1 = {0.f, 0.f, 0.f, 0.f};
      __builtin_amdgcn_s_setprio(1);
      for (int c = 0; c < 6; ++c) {
        bf16x8 kf0 = *(const bf16x8*)(Kb + (size_t)r * 384 + (((c * 4 + g) << 4) ^ rx7));
        sc0 = mfma16(qf[c], kf0, sc0);
      }
      for (int c = 0; c < 6; ++c) {
        bf16x8 kf1 = *(const bf16x8*)(Kb + (size_t)(16 + r) * 384 + (((c * 4 + g) << 4) ^ rx7));
        sc1 = mfma16(qf[c], kf1, sc1);
      }
      __builtin_amdgcn_s_setprio(0);

      int qi_min = qbase + wave * 16;
      if (kv0 + 31 > qi_min) {
        int kj0 = kv0 + r, kj1 = kv0 + 16 + r;
        int qi0 = qi_min + g * 4;
        for (int i = 0; i < 4; ++i) {
          if (kj0 > qi0 + i) sc0[i] = -1e30f;
          if (kj1 > qi0 + i) sc1[i] = -1e30f;
        }
      }

      float tl[4];
      bool ok = true;
      for (int i = 0; i < 4; ++i) {
        tl[i] = fmaxf(sc0[i], sc1[i]);
        ok = ok && (tl[i] - m_r[i] <= DEFER);
      }
      if (!__all(ok)) {
        for (int i = 0; i < 4; ++i) {
          float tm = tl[i];
          for (int off = 1; off < 16; off <<= 1) tm = fmaxf(tm, __shfl_xor(tm, off, 64));
          float mnew = fmaxf(m_r[i], tm);
          float corr = exp2f((m_r[i] - mnew) * sl2);
          lacc[i] *= corr;
          for (int d = 0; d < 8; ++d) acc[d][i] *= corr;
          m_r[i] = mnew;
        }
      }
      float p0[4], p1[4];
      for (int i = 0; i < 4; ++i) {
        p0[i] = exp2f((sc0[i] - m_r[i]) * sl2);
        p1[i] = exp2f((sc1[i] - m_r[i]) * sl2);
      }

      for (int i = 0; i < 4; ++i) {
        Plds[wave][g * 4 + i][r] = f2bf(p0[i]);
        Plds[wave][g * 4 + i][16 + r] = f2bf(p1[i]);
      }
      bf16x8 pa = *(const bf16x8*)&Plds[wave][r][g * 8];
      __builtin_amdgcn_s_setprio(1);
      lacc = mfma16(pa, ones, lacc);
      for (int dt = 0; dt < 8; ++dt) {
        // d = dt*16+r; LDS row = d&63 = (dt&3)*16+r; blk = ((dt>>2)*4+g)^(d&7), d&7==r&7
        bf16x8 vf = *(const bf16x8*)(Vb + (size_t)((dt & 3) * 16 + r) * 128 +
                                     ((((dt >> 2) * 4 + g) << 4) ^ rx7));
        acc[dt] = mfma16(pa, vf, acc[dt]);
      }
      __builtin_amdgcn_s_setprio(0);
      __builtin_amdgcn_sched_barrier(0);
      __builtin_amdgcn_s_barrier();
    }

    if (qt <= 7) {
      for (int i = 0; i < 4; ++i) {
        float inv = 1.0f / lacc[i];
        int row = qbase + wave * 16 + g * 4 + i;
        size_t base = (rb + row) * 2048 + h * 128;
        for (int dt = 0; dt < 8; ++dt)
          ob[base + dt * 16 + r] = f2bf(acc[dt][i] * inv);
      }
    } else {
      unsigned short* op = Opart + (size_t)t * 8192;
      for (int i = 0; i < 4; ++i) {
        int row = wave * 16 + g * 4 + i;
        for (int dt = 0; dt < 8; ++dt)
          op[row * 128 + dt * 16 + r] = f2bf(acc[dt][i]);
        if (r == 0) {
          mlbuf[(size_t)t * 128 + row * 2]     = m_r[i];
          mlbuf[(size_t)t * 128 + row * 2 + 1] = lacc[i];
        }
      }
    }
  }
}

// ---------- merge partials (qt>=8) -> attn bf16 [B*S, 2048] ----------
__global__ void merge_kernel(const unsigned short* __restrict__ Opart,
                             const float* __restrict__ mlbuf,
                             unsigned short* __restrict__ ob) {
  int qt = 8 + (blockIdx.x >> 5), bh = blockIdx.x & 31;
  int b = bh >> 4, h = bh & 15;
  int tid = threadIdx.x;
  int row = tid >> 2, c0 = (tid & 3) * 32;
  const float sl2 = 1.44269504f / 13.8564064605510183f;
  int ns = (qt >= 24) ? 4 : (qt >= 16 ? 3 : 2);

  size_t slot[4];
  float m[4], l[4], w[4];
  float M = -3.0e38f;
#pragma unroll
  for (int j = 0; j < 4; ++j) {
    if (j < ns) {
      slot[j] = task_slot(qt, j, bh);
      m[j] = mlbuf[slot[j] * 128 + row * 2];
      l[j] = mlbuf[slot[j] * 128 + row * 2 + 1];
      M = fmaxf(M, m[j]);
    }
  }
  float L = 0.f;
#pragma unroll
  for (int j = 0; j < 4; ++j)
    if (j < ns) { w[j] = exp2f((m[j] - M) * sl2); L += w[j] * l[j]; }
  float invL = 1.f / L;
#pragma unroll
  for (int j = 0; j < 4; ++j) if (j < ns) w[j] *= invL;

  float o[32];
#pragma unroll
  for (int e = 0; e < 32; ++e) o[e] = 0.f;
#pragma unroll
  for (int j = 0; j < 4; ++j) {
    if (j < ns) {
      const unsigned short* pp = Opart + slot[j] * 8192 + row * 128 + c0;
      for (int blk = 0; blk < 4; ++blk) {
        us8 v = *(const us8*)(pp + blk * 8);
        for (int e = 0; e < 8; ++e) o[blk * 8 + e] += w[j] * b2f(v[e]);
      }
    }
  }
  size_t obase = ((size_t)b * 2048 + qt * 64 + row) * 2048 + h * 128 + c0;
  for (int blk = 0; blk < 4; ++blk) {
    us8 st;
    for (int e = 0; e < 8; ++e) st[e] = f2bf(o[blk * 8 + e]);
    *(us8*)(ob + obase + blk * 8) = st;
  }
}

// ---------- launcher ----------
extern "C" void kernel_launch(void* const* d_in, const int* in_sizes, int n_in,
                              void* d_out, int out_size, void* d_ws, size_t ws_size,
                              hipStream_t stream) {
  const float* x      = (const float*)d_in[0];
  const float* w_qkv  = (const float*)d_in[1];
  const float* b_qkv  = (const float*)d_in[2];
  const float* w_qup  = (const float*)d_in[3];
  const float* b_qup  = (const float*)d_in[4];
  const float* w_kup  = (const float*)d_in[5];
  const float* b_kup  = (const float*)d_in[6];
  const float* w_vup  = (const float*)d_in[7];
  const float* b_vup  = (const float*)d_in[8];
  const float* w_qpos = (const float*)d_in[9];
  const float* b_qpos = (const float*)d_in[10];
  const float* w_kpos = (const float*)d_in[11];
  const float* b_kpos = (const float*)d_in[12];
  const float* w_o    = (const float*)d_in[13];
  const float* b_o    = (const float*)d_in[14];
  (void)in_sizes; (void)n_in; (void)out_size; (void)ws_size;

  char* ws = (char*)d_ws;
  size_t off = 0;
  auto alloc = [&](size_t bytes) -> char* {
    char* p = ws + off;
    off += (bytes + 255) & ~(size_t)255;
    return p;
  };

  unsigned short* wB1    = (unsigned short*)alloc(8388608);   // [2048,2048] (rows 1600+ zero)
  unsigned short* wB2q   = (unsigned short*)alloc(3145728);   // [3072,512]
  unsigned short* wB2k   = (unsigned short*)alloc(2097152);   // [2048,512]
  unsigned short* wB2v   = (unsigned short*)alloc(2097152);   // [2048,512]
  unsigned short* wBo    = (unsigned short*)alloc(8388608);   // [2048,2048]
  float*          bias1  = (float*)alloc(2048 * 4);
  float*          bias2q = (float*)alloc(3072 * 4);
  float*          costab = (float*)alloc(262144);
  float*          sintab = (float*)alloc(262144);
  unsigned short* latext = (unsigned short*)alloc(16777216);  // [4096,2048]
  unsigned short* tmp_q  = (unsigned short*)alloc(25165824);  // [4096,3072]
  unsigned short* tmp_k  = (unsigned short*)alloc(16777216);  // [4096,2048]
  unsigned short* vTbuf  = (unsigned short*)alloc(16777216);  // [32,128,2048]
  unsigned short* posqr  = (unsigned short*)alloc(8388608);   // [4096,1024]
  unsigned short* poskr  = (unsigned short*)alloc(524288);    // [4096,64]
  unsigned short* Opart  = (unsigned short*)alloc(41943040);  // [2560][64][128] bf16
  float*          mlbuf  = (float*)alloc(1310720);            // [2560][64][2]
  int*            counter= (int*)alloc(256);
  unsigned short* attnb  = (unsigned short*)alloc(16777216);  // [4096,2048] bf16

  // 1. fused prep: rope tables, biases, pad, counter reset, 7 weight transposes
  prep_all_kernel<<<11392, 256, 0, stream>>>(b_qkv, b_kpos, b_qup, b_qpos,
                                             bias1, bias2q, costab, sintab, wB1,
                                             w_qkv, w_kpos, w_qup, w_qpos, w_kup,
                                             w_vup, w_o, wB2q, wB2k, wB2v, wBo,
                                             counter);
  // 2. GEMM1 (fp32 A direct): latext[4096,2048] = x @ wB1^T + bias1 (cols 1664+ dead)
  gemm_a32_kernel<<<512, 256, 0, stream>>>(x, 2048, wB1, 2048,
                                           latext, 2048, bias1, 2048, 16);
  // 3. up-projections (K=512); v-up writes vT directly
  gemm_bt_kernel<0><<<768, 256, 0, stream>>>(latext, 2048, wB2q, 512,
                                             tmp_q, 3072, bias2q, 512, 24);
  gemm_bt_kernel<0><<<512, 256, 0, stream>>>(latext + 512, 2048, wB2k, 512,
                                             tmp_k, 2048, b_kup, 512, 16);
  gemm_bt_kernel<2><<<512, 256, 0, stream>>>(latext + 1024, 2048, wB2v, 512,
                                             vTbuf, 2048, b_vup, 512, 16);
  // 4. rope
  rope_kernel<<<2176, 256, 0, stream>>>(tmp_q, latext, costab, sintab, posqr, poskr);
  // 5. flash attention (KVBLK=32, grid 1280, conflict-free V layout)
  flash_kernel<<<1280, 256, 0, stream>>>(tmp_q, tmp_k, posqr, poskr, vTbuf,
                                         attnb, Opart, mlbuf, counter);
  // 6. merge partials (qt>=8) -> attnb
  merge_kernel<<<768, 256, 0, stream>>>(Opart, mlbuf, attnb);
  // 7. output projection (fp32 out + b_o)
  gemm_bt_kernel<1><<<512, 256, 0, stream>>>(attnb, 2048, wBo, 2048,
                                             d_out, 2048, b_o, 2048, 16);
}

// Round 17
// 270.222 us; speedup vs baseline: 1.0676x; 1.0377x over previous
//
#include <hip/hip_runtime.h>
#include <cstdint>
#include <cstddef>

// ---------- types ----------
typedef __bf16 bf16x8 __attribute__((ext_vector_type(8)));
typedef float  f32x4  __attribute__((ext_vector_type(4)));
typedef unsigned short us8 __attribute__((ext_vector_type(8)));
typedef unsigned short us4 __attribute__((ext_vector_type(4)));

__device__ __forceinline__ unsigned short f2bf(float f) {
  union { float f; unsigned u; } v; v.f = f;
  unsigned r = v.u + 0x7FFFu + ((v.u >> 16) & 1u);
  return (unsigned short)(r >> 16);
}
__device__ __forceinline__ float b2f(unsigned short h) {
  union { unsigned u; float f; } v; v.u = ((unsigned)h) << 16;
  return v.f;
}
__device__ __forceinline__ f32x4 mfma16(bf16x8 a, bf16x8 b, f32x4 c) {
  return __builtin_amdgcn_mfma_f32_16x16x32_bf16(a, b, c, 0, 0, 0);
}
// async global->LDS, 16B per lane; lds dest wave-uniform (HW writes base + lane*16)
__device__ __forceinline__ void gl_lds16(const unsigned short* g, unsigned short* l) {
  __builtin_amdgcn_global_load_lds(
      (const __attribute__((address_space(1))) void*)g,
      (__attribute__((address_space(3))) void*)l, 16, 0, 0);
}

// ---------- fused prep: rope tables + biases + pad + counters + 7 weight transposes ----------
__global__ void prep_all_kernel(const float* __restrict__ b_qkv,
                                const float* __restrict__ b_kpos,
                                const float* __restrict__ b_qup,
                                const float* __restrict__ b_qpos,
                                float* __restrict__ bias1,
                                float* __restrict__ bias2q,
                                float* __restrict__ costab,
                                float* __restrict__ sintab,
                                unsigned short* __restrict__ wB1,
                                const float* __restrict__ w_qkv,
                                const float* __restrict__ w_kpos,
                                const float* __restrict__ w_qup,
                                const float* __restrict__ w_qpos,
                                const float* __restrict__ w_kup,
                                const float* __restrict__ w_vup,
                                const float* __restrict__ w_o,
                                unsigned short* __restrict__ wB2q,
                                unsigned short* __restrict__ wB2k,
                                unsigned short* __restrict__ wB2v,
                                unsigned short* __restrict__ wBo,
                                int* __restrict__ counters) {
  __shared__ float tile[32][33];
  int blk = blockIdx.x;
  if (blk < 512) {
    int i = blk * 256 + threadIdx.x;   // covers 131072
    if (i < 65536) {                   // 2048 x 32 rope tables
      int s = i >> 5, f = i & 31;
      float inv = powf(50000.0f, -(float)f / 32.0f);
      float a = (float)s * inv;
      costab[i] = cosf(a);
      sintab[i] = sinf(a);
    }
    if (i < 2048) bias1[i] = (i < 1536) ? b_qkv[i] : (i < 1600 ? b_kpos[i - 1536] : 0.0f);
    if (i < 3072) bias2q[i] = (i < 2048) ? b_qup[i] : b_qpos[i - 2048];
    for (int jj = 0; jj < 7; ++jj)
      wB1[(size_t)1600 * 2048 + (size_t)jj * 131072 + i] = 0;
    if (i < 64) counters[i] = 0;       // flash steal counter reset
    return;
  }
  const float* in;
  unsigned short* out;
  int ldin, ldo, nx, j;
  if (blk < 3584)      { j = blk - 512;  in = w_qkv;  ldin = 1536; out = wB1;                        ldo = 2048; nx = 48; }
  else if (blk < 3712) { j = blk - 3584; in = w_kpos; ldin = 64;   out = wB1 + (size_t)1536 * 2048;  ldo = 2048; nx = 2;  }
  else if (blk < 4736) { j = blk - 3712; in = w_qup;  ldin = 2048; out = wB2q;                       ldo = 512;  nx = 64; }
  else if (blk < 5248) { j = blk - 4736; in = w_qpos; ldin = 1024; out = wB2q + (size_t)2048 * 512;  ldo = 512;  nx = 32; }
  else if (blk < 6272) { j = blk - 5248; in = w_kup;  ldin = 2048; out = wB2k;                       ldo = 512;  nx = 64; }
  else if (blk < 7296) { j = blk - 6272; in = w_vup;  ldin = 2048; out = wB2v;                       ldo = 512;  nx = 64; }
  else                 { j = blk - 7296; in = w_o;    ldin = 2048; out = wBo;                        ldo = 2048; nx = 64; }
  int c0 = (j % nx) * 32, r0 = (j / nx) * 32;
  int tx = threadIdx.x & 31, ty = threadIdx.x >> 5;
  for (int jj = 0; jj < 4; ++jj)
    tile[ty + jj * 8][tx] = in[(size_t)(r0 + ty + jj * 8) * ldin + c0 + tx];
  __syncthreads();
  for (int jj = 0; jj < 4; ++jj)
    out[(size_t)(c0 + ty + jj * 8) * ldo + r0 + tx] = f2bf(tile[tx][ty + jj * 8]);
}

// ---------- XCD-aware bijective block remap over a local range ----------
__device__ __forceinline__ void xcd_decode_n(int lbid, int nwg, int nx, int& bx, int& by) {
  int cpx = nwg >> 3;
  int wg = (lbid & 7) * cpx + (lbid >> 3);
  bx = wg % nx;
  by = wg / nx;
}
__device__ __forceinline__ void xcd_decode(int nx, int& bx, int& by) {
  xcd_decode_n(blockIdx.x, gridDim.x, nx, bx, by);
}

// ---------- shared GEMM body: C[M,N] = A[M,K]*Bt[N,K]^T + bias ----------
// mode: 0 = bf16 row-major, 1 = f32 row-major, 2 = bf16 transposed (vT epilogue).
// smem must be 32768 shorts. Runtime mode is block-uniform.
__device__ __forceinline__
void gemm_body(unsigned short* smem,
               const unsigned short* __restrict__ A, int lda,
               const unsigned short* __restrict__ Bt, int ldb,
               void* __restrict__ Cout, int ldc,
               const float* __restrict__ bias, int K,
               long brow, long bcol, int mode) {
  int tid = threadIdx.x;
  int wave = tid >> 6, lane = tid & 63;
  int g = lane >> 4, r = lane & 15;
  int wr = wave >> 1, wc = wave & 1;

  int srowl = lane >> 3;
  int sw = ((lane & 7) ^ (srowl & 7)) * 8;
  const unsigned short* Abase = A + (brow + wave * 32 + srowl) * (long)lda + sw;
  const unsigned short* Bbase = Bt + (bcol + wave * 32 + srowl) * (long)ldb + sw;

  f32x4 acc[4][4];
  for (int mi = 0; mi < 4; ++mi)
    for (int ni = 0; ni < 4; ++ni)
      acc[mi][ni] = f32x4{0.f, 0.f, 0.f, 0.f};

  auto stage = [&](int buf, int k0) {
    unsigned short* ab = smem + buf * 16384;
    unsigned short* bb = ab + 8192;
    for (int c = 0; c < 4; ++c) {
      gl_lds16(Abase + (size_t)c * 8 * lda + k0, ab + (wave * 32 + c * 8) * 64);
      gl_lds16(Bbase + (size_t)c * 8 * ldb + k0, bb + (wave * 32 + c * 8) * 64);
    }
  };

  int rx = (r & 7) << 4;
  int nt = K >> 6;

  stage(0, 0);
  for (int t = 0; t < nt; ++t) {
    if (t + 1 < nt) {
      stage((t + 1) & 1, (t + 1) << 6);
      asm volatile("s_waitcnt vmcnt(8)" ::: "memory");
    } else {
      asm volatile("s_waitcnt vmcnt(0)" ::: "memory");
    }
    __builtin_amdgcn_sched_barrier(0);
    __builtin_amdgcn_s_barrier();
    __builtin_amdgcn_sched_barrier(0);
    const char* Ab = (const char*)(smem + (t & 1) * 16384);
    const char* Bb = Ab + 16384;
    for (int kk = 0; kk < 2; ++kk) {
      bf16x8 af[4], bfv[4];
      for (int mi = 0; mi < 4; ++mi)
        af[mi] = *(const bf16x8*)(Ab + (size_t)(wr * 64 + mi * 16 + r) * 128 +
                                  ((kk * 64 + g * 16) ^ rx));
      for (int ni = 0; ni < 4; ++ni)
        bfv[ni] = *(const bf16x8*)(Bb + (size_t)(wc * 64 + ni * 16 + r) * 128 +
                                   ((kk * 64 + g * 16) ^ rx));
      for (int mi = 0; mi < 4; ++mi)
        for (int ni = 0; ni < 4; ++ni)
          acc[mi][ni] = mfma16(af[mi], bfv[ni], acc[mi][ni]);
    }
    __builtin_amdgcn_sched_barrier(0);
    __builtin_amdgcn_s_barrier();
  }

  if (mode == 2) {
    // transposed epilogue -> vT[bh][d][s]; smem reused as [128][136] scratch (17408 shorts)
    for (int mi = 0; mi < 4; ++mi)
      for (int ni = 0; ni < 4; ++ni) {
        int col = wc * 64 + ni * 16 + r;
        float bv = bias[bcol + col];
        int rowb = wr * 64 + mi * 16 + g * 4;
        for (int i = 0; i < 4; ++i)
          smem[col * 136 + rowb + i] = f2bf(acc[mi][ni][i] + bv);
      }
    __syncthreads();
    int col = tid >> 1, half = tid & 1;
    int bh = (int)(brow >> 11) * 16 + (int)(bcol >> 7);
    unsigned short* outp = (unsigned short*)Cout +
                           ((size_t)bh * 128 + col) * 2048 + (brow & 2047);
    for (int j = 0; j < 8; ++j) {
      int row0 = half * 64 + j * 8;
      *(us8*)(outp + row0) = *(const us8*)&smem[col * 136 + row0];
    }
    return;
  }

  for (int mi = 0; mi < 4; ++mi)
    for (int ni = 0; ni < 4; ++ni) {
      long col = bcol + wc * 64 + ni * 16 + r;
      float bv = bias ? bias[col] : 0.0f;
      long rowb = brow + wr * 64 + mi * 16 + g * 4;
      for (int i = 0; i < 4; ++i) {
        float v = acc[mi][ni][i] + bv;
        if (mode == 1)
          ((float*)Cout)[(rowb + i) * (long)ldc + col] = v;
        else
          ((unsigned short*)Cout)[(rowb + i) * (long)ldc + col] = f2bf(v);
      }
    }
}

// ---------- standalone GEMM (o-proj) ----------
template <int OUT_MODE>
__global__ __launch_bounds__(256, 2)
void gemm_bt_kernel(const unsigned short* __restrict__ A, int lda,
                    const unsigned short* __restrict__ Bt, int ldb,
                    void* __restrict__ Cout, int ldc,
                    const float* __restrict__ bias, int K, int nx) {
  __shared__ unsigned short smem[32768];
  int bx, by;
  xcd_decode(nx, bx, by);
  gemm_body(smem, A, lda, Bt, ldb, Cout, ldc, bias, K,
            (long)by * 128, (long)bx * 128, OUT_MODE);
}

// ---------- fused up-projections: q-up (768) | k-up (512) | v-up transposed (512) ----------
__global__ __launch_bounds__(256, 2)
void gemm_up3_kernel(const unsigned short* __restrict__ latext,
                     const unsigned short* __restrict__ wB2q,
                     const unsigned short* __restrict__ wB2k,
                     const unsigned short* __restrict__ wB2v,
                     unsigned short* __restrict__ tmp_q,
                     unsigned short* __restrict__ tmp_k,
                     unsigned short* __restrict__ vTbuf,
                     const float* __restrict__ bias2q,
                     const float* __restrict__ b_kup,
                     const float* __restrict__ b_vup) {
  __shared__ unsigned short smem[32768];
  int bid = blockIdx.x;
  const unsigned short* A;
  const unsigned short* Bt;
  void* C;
  const float* bias;
  int ldc, nx, mode, lbid, nwg;
  if (bid < 768)       { lbid = bid;        nwg = 768; nx = 24; A = latext;        Bt = wB2q; C = tmp_q; ldc = 3072; bias = bias2q; mode = 0; }
  else if (bid < 1280) { lbid = bid - 768;  nwg = 512; nx = 16; A = latext + 512;  Bt = wB2k; C = tmp_k; ldc = 2048; bias = b_kup;  mode = 0; }
  else                 { lbid = bid - 1280; nwg = 512; nx = 16; A = latext + 1024; Bt = wB2v; C = vTbuf; ldc = 2048; bias = b_vup;  mode = 2; }
  int bx, by;
  xcd_decode_n(lbid, nwg, nx, bx, by);
  gemm_body(smem, A, 2048, Bt, 512, C, ldc, bias, 512,
            (long)by * 128, (long)bx * 128, mode);
}

// ---------- GEMM1: A is fp32 (x), reg-staged with in-register bf16 convert; B bf16 ----------
__global__ __launch_bounds__(256, 2)
void gemm_a32_kernel(const float* __restrict__ A, int lda,
                     const unsigned short* __restrict__ Bt, int ldb,
                     unsigned short* __restrict__ Cout, int ldc,
                     const float* __restrict__ bias, int K, int nx) {
  __shared__ unsigned short smem[32768];   // A bufs [0,16384), B bufs [16384,32768)
  int tid = threadIdx.x;
  int wave = tid >> 6, lane = tid & 63;
  int g = lane >> 4, r = lane & 15;
  int wr = wave >> 1, wc = wave & 1;
  int bx, by;
  xcd_decode(nx, bx, by);
  long brow = (long)by * 128, bcol = (long)bx * 128;

  int f4c = tid & 15, row0 = tid >> 4;
  int ablk = f4c >> 1, asub = (f4c & 1) * 8;
  const float4* Ag = (const float4*)(A + (brow + row0) * (size_t)lda) + f4c;

  int srowl = lane >> 3;
  int sw = ((lane & 7) ^ (srowl & 7)) * 8;
  const unsigned short* Bbase = Bt + (bcol + wave * 32 + srowl) * (long)ldb + sw;

  f32x4 acc[4][4];
  for (int mi = 0; mi < 4; ++mi)
    for (int ni = 0; ni < 4; ++ni)
      acc[mi][ni] = f32x4{0.f, 0.f, 0.f, 0.f};

  auto stage_b = [&](int buf, int k0) {
    unsigned short* bb = smem + 16384 + buf * 8192;
    for (int c = 0; c < 4; ++c)
      gl_lds16(Bbase + (size_t)c * 8 * ldb + k0, bb + (wave * 32 + c * 8) * 64);
  };

  int rx = (r & 7) << 4;
  int nt = K >> 6;

  float4 areg[8];
#pragma unroll
  for (int s = 0; s < 8; ++s) areg[s] = Ag[(size_t)s * 8192];
  stage_b(0, 0);

  for (int t = 0; t < nt; ++t) {
    char* alds = (char*)(smem + (t & 1) * 8192);
#pragma unroll
    for (int s = 0; s < 8; ++s) {
      us4 hv;
      hv[0] = f2bf(areg[s].x); hv[1] = f2bf(areg[s].y);
      hv[2] = f2bf(areg[s].z); hv[3] = f2bf(areg[s].w);
      int row = row0 + s * 16;
      *(us4*)(alds + row * 128 + ((ablk ^ (row & 7)) << 4) + asub) = hv;
    }
    asm volatile("s_waitcnt vmcnt(0)" ::: "memory");   // B(t) landed
    asm volatile("s_waitcnt lgkmcnt(0)" ::: "memory"); // A ds_writes committed
    __builtin_amdgcn_sched_barrier(0);
    __builtin_amdgcn_s_barrier();
    __builtin_amdgcn_sched_barrier(0);
    if (t + 1 < nt) {
      int k1 = (t + 1) << 6;
#pragma unroll
      for (int s = 0; s < 8; ++s) areg[s] = Ag[(size_t)s * 8192 + (k1 >> 2)];
      stage_b((t + 1) & 1, k1);
    }
    const char* Ab = (const char*)(smem + (t & 1) * 8192);
    const char* Bb = (const char*)(smem + 16384 + (t & 1) * 8192);
    for (int kk = 0; kk < 2; ++kk) {
      bf16x8 af[4], bfv[4];
      for (int mi = 0; mi < 4; ++mi)
        af[mi] = *(const bf16x8*)(Ab + (size_t)(wr * 64 + mi * 16 + r) * 128 +
                                  ((kk * 64 + g * 16) ^ rx));
      for (int ni = 0; ni < 4; ++ni)
        bfv[ni] = *(const bf16x8*)(Bb + (size_t)(wc * 64 + ni * 16 + r) * 128 +
                                   ((kk * 64 + g * 16) ^ rx));
      for (int mi = 0; mi < 4; ++mi)
        for (int ni = 0; ni < 4; ++ni)
          acc[mi][ni] = mfma16(af[mi], bfv[ni], acc[mi][ni]);
    }
    __builtin_amdgcn_sched_barrier(0);
    __builtin_amdgcn_s_barrier();
  }

  for (int mi = 0; mi < 4; ++mi)
    for (int ni = 0; ni < 4; ++ni) {
      long col = bcol + wc * 64 + ni * 16 + r;
      float bv = bias[col];
      long rowb = brow + wr * 64 + mi * 16 + g * 4;
      for (int i = 0; i < 4; ++i)
        Cout[(rowb + i) * (long)ldc + col] = f2bf(acc[mi][ni][i] + bv);
    }
}

// ---------- rope: posqr[4096][1024] (per-head 64) and poskr[4096][64], vectorized ----------
__global__ void rope_kernel(const unsigned short* __restrict__ tmp_q,
                            const unsigned short* __restrict__ latext,
                            const float* __restrict__ costab,
                            const float* __restrict__ sintab,
                            unsigned short* __restrict__ posqr,
                            unsigned short* __restrict__ poskr) {
  int idx = blockIdx.x * 256 + threadIdx.x;  // 524288 posq + 32768 posk = 557056
  const unsigned short* src;
  unsigned short* dst;
  int s, dp0;
  if (idx < 524288) {
    int rowA = idx >> 7, rem = idx & 127;
    int h = rem >> 3;
    dp0 = (rem & 7) * 8;
    s = rowA & 2047;
    src = tmp_q + (size_t)rowA * 3072 + 2048 + h * 64;
    dst = posqr + (size_t)rowA * 1024 + h * 64 + dp0;
  } else if (idx < 557056) {
    int j = idx - 524288;
    int rowA = j >> 3;
    dp0 = (j & 7) * 8;
    s = rowA & 2047;
    src = latext + (size_t)rowA * 2048 + 1536;
    dst = poskr + (size_t)rowA * 64 + dp0;
  } else {
    return;
  }
  us8 x1 = *(const us8*)(src + dp0);
  us8 x2 = *(const us8*)(src + (dp0 ^ 32));
  int f0 = dp0 & 31;
  const float* cp = costab + s * 32 + f0;
  const float* sp = sintab + s * 32 + f0;
  bool low = dp0 < 32;
  us8 o;
  for (int e = 0; e < 8; ++e) {
    float a = b2f(x1[e]), b = b2f(x2[e]);
    float v = low ? (a * cp[e] - b * sp[e]) : (a * cp[e] + b * sp[e]);
    o[e] = f2bf(v);
  }
  *(us8*)dst = o;
}

// ---------- task decode: 2560 tasks (QBLK=64, <=16 chunks/seg), longest-first ----------
__device__ __forceinline__ void task_decode(int t, int& qt, int& seg, int& bh) {
  if (t < 1024) {
    qt = 31 - (t >> 7); int rem = t & 127; seg = rem >> 5; bh = rem & 31;
  } else if (t < 1792) {
    int t2 = t - 1024; int qi = t2 / 96; int rem = t2 - qi * 96;
    qt = 23 - qi; seg = rem >> 5; bh = rem & 31;
  } else if (t < 2304) {
    int t3 = t - 1792; qt = 15 - (t3 >> 6); int rem = t3 & 63; seg = rem >> 5; bh = rem & 31;
  } else {
    int t4 = t - 2304; qt = 7 - (t4 >> 5); seg = 0; bh = t4 & 31;
  }
}
__device__ __forceinline__ int task_slot(int qt, int seg, int bh) {
  if (qt >= 24) return (31 - qt) * 128 + seg * 32 + bh;
  if (qt >= 16) return 1024 + (23 - qt) * 96 + seg * 32 + bh;
  return 1792 + (15 - qt) * 64 + seg * 32 + bh;
}

// ---------- persistent split-KV causal flash attention (R16, conflict-free V) ----------
__global__ __launch_bounds__(256, 2)
void flash_kernel(const unsigned short* __restrict__ tmp_q,
                  const unsigned short* __restrict__ tmp_k,
                  const unsigned short* __restrict__ posqr,
                  const unsigned short* __restrict__ poskr,
                  const unsigned short* __restrict__ vT,
                  unsigned short* __restrict__ ob,
                  unsigned short* __restrict__ Opart,
                  float* __restrict__ mlbuf,
                  int* __restrict__ counter) {
  const int S = 2048;
  int tid = threadIdx.x, wave = tid >> 6, lane = tid & 63;
  int g = lane >> 4, r = lane & 15;
  const float sl2 = 1.44269504f / 13.8564064605510183f;  // log2e / sqrt(192)
  const float DEFER = 96.0f;

  __shared__ unsigned short Klds[32 * 192];   // 32 rows x 384B, blk16 ^= row&7
  __shared__ unsigned short Vlds[64 * 64];    // 64 rows x 128B: d-rows d,(d+64); blk ^= d&7
  __shared__ unsigned short Plds[4][16][40];
  __shared__ int s_tile;
  char* Kb = (char*)Klds;
  char* Vb = (char*)Vlds;
  int rx7 = (r & 7) << 4;

  us8 onesu;
  for (int e = 0; e < 8; ++e) onesu[e] = 0x3F80;
  bf16x8 ones = *(const bf16x8*)&onesu;

  int kn_row[2], kn_seg[2];
  for (int j = 0; j < 2; ++j) {
    int slot = j * 256 + tid;
    kn_row[j] = slot >> 4;
    kn_seg[j] = slot & 15;
  }
  int kr_row = tid >> 3, kr_seg = tid & 7;
  int v_row[2], v_seg[2];
  for (int j = 0; j < 2; ++j) {
    int slot = j * 256 + tid;
    v_row[j] = slot >> 2;      // global d-row 0..127
    v_seg[j] = slot & 3;       // 16B chunk within staged 32 shorts
  }

  for (;;) {
    if (tid == 0) s_tile = atomicAdd(counter, 1);
    __syncthreads();
    int t = s_tile;
    if (t >= 2560) return;
    int qt, seg, bh;
    task_decode(t, qt, seg, bh);
    int b = bh >> 4, h = bh & 15;
    int qbase = qt * 64;
    int cbeg = seg * 16;
    int cend = min(cbeg + 16, 2 * (qt + 1));
    size_t rb = (size_t)b * 2048;

    const unsigned short* kpn = tmp_k + rb * 2048 + h * 128;
    const unsigned short* kpr = poskr + rb * 64;
    const unsigned short* vp = vT + (size_t)bh * 128 * S;

    bf16x8 qf[6];
    {
      size_t qrowA = rb + qbase + wave * 16 + r;
      const unsigned short* qn = tmp_q + qrowA * 3072 + h * 128 + g * 8;
      for (int c = 0; c < 4; ++c) qf[c] = *(const bf16x8*)(qn + c * 32);
      const unsigned short* qr_ = posqr + qrowA * 1024 + h * 64 + g * 8;
      qf[4] = *(const bf16x8*)(qr_);
      qf[5] = *(const bf16x8*)(qr_ + 32);
    }

    f32x4 acc[8];
    for (int d = 0; d < 8; ++d) acc[d] = f32x4{0.f, 0.f, 0.f, 0.f};
    f32x4 lacc = {0.f, 0.f, 0.f, 0.f};
    float m_r[4];
    for (int i = 0; i < 4; ++i) m_r[i] = -3.0e38f;

    us8 kreg[2], krope, vreg[2];
    {
      int kv0 = cbeg * 32;
      for (int j = 0; j < 2; ++j)
        kreg[j] = *(const us8*)(kpn + (size_t)(kv0 + kn_row[j]) * 2048 + kn_seg[j] * 8);
      krope = *(const us8*)(kpr + (size_t)(kv0 + kr_row) * 64 + kr_seg * 8);
      for (int j = 0; j < 2; ++j)
        vreg[j] = *(const us8*)(vp + (size_t)v_row[j] * S + kv0 + v_seg[j] * 8);
    }

    for (int ch = cbeg; ch < cend; ++ch) {
      for (int j = 0; j < 2; ++j)
        *(us8*)(Kb + (size_t)kn_row[j] * 384 +
                ((kn_seg[j] ^ (kn_row[j] & 7)) << 4)) = kreg[j];
      *(us8*)(Kb + (size_t)kr_row * 384 +
              (((16 + kr_seg) ^ (kr_row & 7)) << 4)) = krope;
      for (int j = 0; j < 2; ++j) {
        int d = v_row[j];
        *(us8*)(Vb + (size_t)(d & 63) * 128 +
                ((((d >> 6) * 4 + v_seg[j]) ^ (d & 7)) << 4)) = vreg[j];
      }
      asm volatile("s_waitcnt lgkmcnt(0)" ::: "memory");
      __builtin_amdgcn_sched_barrier(0);
      __builtin_amdgcn_s_barrier();
      __builtin_amdgcn_sched_barrier(0);
      if (ch + 1 < cend) {
        int kv1 = (ch + 1) * 32;
        for (int j = 0; j < 2; ++j)
          kreg[j] = *(const us8*)(kpn + (size_t)(kv1 + kn_row[j]) * 2048 + kn_seg[j] * 8);
        krope = *(const us8*)(kpr + (size_t)(kv1 + kr_row) * 64 + kr_seg * 8);
        for (int j = 0; j < 2; ++j)
          vreg[j] = *(const us8*)(vp + (size_t)v_row[j] * S + kv1 + v_seg[j] * 8);
      }
      int kv0 = ch * 32;

      f32x4 sc0 = {0.f, 0.f, 0.f, 0.f}, sc1 = {0.f, 0.f, 0.f, 0.f};
      __builtin_amdgcn_s_setprio(1);
      for (int c = 0; c < 6; ++c) {
        bf16x8 kf0 = *(const bf16x8*)(Kb + (size_t)r * 384 + (((c * 4 + g) << 4) ^ rx7));
        sc0 = mfma16(qf[c], kf0, sc0);
      }
      for (int c = 0; c < 6; ++c) {
        bf16x8 kf1 = *(const bf16x8*)(Kb + (size_t)(16 + r) * 384 + (((c * 4 + g) << 4) ^ rx7));
        sc1 = mfma16(qf[c], kf1, sc1);
      }
      __builtin_amdgcn_s_setprio(0);

      int qi_min = qbase + wave * 16;
      if (kv0 + 31 > qi_min) {
        int kj0 = kv0 + r, kj1 = kv0 + 16 + r;
        int qi0 = qi_min + g * 4;
        for (int i = 0; i < 4; ++i) {
          if (kj0 > qi0 + i) sc0[i] = -1e30f;
          if (kj1 > qi0 + i) sc1[i] = -1e30f;
        }
      }

      float tl[4];
      bool ok = true;
      for (int i = 0; i < 4; ++i) {
        tl[i] = fmaxf(sc0[i], sc1[i]);
        ok = ok && (tl[i] - m_r[i] <= DEFER);
      }
      if (!__all(ok)) {
        for (int i = 0; i < 4; ++i) {
          float tm = tl[i];
          for (int off = 1; off < 16; off <<= 1) tm = fmaxf(tm, __shfl_xor(tm, off, 64));
          float mnew = fmaxf(m_r[i], tm);
          float corr = exp2f((m_r[i] - mnew) * sl2);
          lacc[i] *= corr;
          for (int d = 0; d < 8; ++d) acc[d][i] *= corr;
          m_r[i] = mnew;
        }
      }
      float p0[4], p1[4];
      for (int i = 0; i < 4; ++i) {
        p0[i] = exp2f((sc0[i] - m_r[i]) * sl2);
        p1[i] = exp2f((sc1[i] - m_r[i]) * sl2);
      }

      for (int i = 0; i < 4; ++i) {
        Plds[wave][g * 4 + i][r] = f2bf(p0[i]);
        Plds[wave][g * 4 + i][16 + r] = f2bf(p1[i]);
      }
      bf16x8 pa = *(const bf16x8*)&Plds[wave][r][g * 8];
      __builtin_amdgcn_s_setprio(1);
      lacc = mfma16(pa, ones, lacc);
      for (int dt = 0; dt < 8; ++dt) {
        bf16x8 vf = *(const bf16x8*)(Vb + (size_t)((dt & 3) * 16 + r) * 128 +
                                     ((((dt >> 2) * 4 + g) << 4) ^ rx7));
        acc[dt] = mfma16(pa, vf, acc[dt]);
      }
      __builtin_amdgcn_s_setprio(0);
      __builtin_amdgcn_sched_barrier(0);
      __builtin_amdgcn_s_barrier();
    }

    if (qt <= 7) {
      for (int i = 0; i < 4; ++i) {
        float inv = 1.0f / lacc[i];
        int row = qbase + wave * 16 + g * 4 + i;
        size_t base = (rb + row) * 2048 + h * 128;
        for (int dt = 0; dt < 8; ++dt)
          ob[base + dt * 16 + r] = f2bf(acc[dt][i] * inv);
      }
    } else {
      unsigned short* op = Opart + (size_t)t * 8192;
      for (int i = 0; i < 4; ++i) {
        int row = wave * 16 + g * 4 + i;
        for (int dt = 0; dt < 8; ++dt)
          op[row * 128 + dt * 16 + r] = f2bf(acc[dt][i]);
        if (r == 0) {
          mlbuf[(size_t)t * 128 + row * 2]     = m_r[i];
          mlbuf[(size_t)t * 128 + row * 2 + 1] = lacc[i];
        }
      }
    }
  }
}

// ---------- merge partials (qt>=8) -> attn bf16 [B*S, 2048] ----------
__global__ void merge_kernel(const unsigned short* __restrict__ Opart,
                             const float* __restrict__ mlbuf,
                             unsigned short* __restrict__ ob) {
  int qt = 8 + (blockIdx.x >> 5), bh = blockIdx.x & 31;
  int b = bh >> 4, h = bh & 15;
  int tid = threadIdx.x;
  int row = tid >> 2, c0 = (tid & 3) * 32;
  const float sl2 = 1.44269504f / 13.8564064605510183f;
  int ns = (qt >= 24) ? 4 : (qt >= 16 ? 3 : 2);

  size_t slot[4];
  float m[4], l[4], w[4];
  float M = -3.0e38f;
#pragma unroll
  for (int j = 0; j < 4; ++j) {
    if (j < ns) {
      slot[j] = task_slot(qt, j, bh);
      m[j] = mlbuf[slot[j] * 128 + row * 2];
      l[j] = mlbuf[slot[j] * 128 + row * 2 + 1];
      M = fmaxf(M, m[j]);
    }
  }
  float L = 0.f;
#pragma unroll
  for (int j = 0; j < 4; ++j)
    if (j < ns) { w[j] = exp2f((m[j] - M) * sl2); L += w[j] * l[j]; }
  float invL = 1.f / L;
#pragma unroll
  for (int j = 0; j < 4; ++j) if (j < ns) w[j] *= invL;

  float o[32];
#pragma unroll
  for (int e = 0; e < 32; ++e) o[e] = 0.f;
#pragma unroll
  for (int j = 0; j < 4; ++j) {
    if (j < ns) {
      const unsigned short* pp = Opart + slot[j] * 8192 + row * 128 + c0;
      for (int blk = 0; blk < 4; ++blk) {
        us8 v = *(const us8*)(pp + blk * 8);
        for (int e = 0; e < 8; ++e) o[blk * 8 + e] += w[j] * b2f(v[e]);
      }
    }
  }
  size_t obase = ((size_t)b * 2048 + qt * 64 + row) * 2048 + h * 128 + c0;
  for (int blk = 0; blk < 4; ++blk) {
    us8 st;
    for (int e = 0; e < 8; ++e) st[e] = f2bf(o[blk * 8 + e]);
    *(us8*)(ob + obase + blk * 8) = st;
  }
}

// ---------- launcher ----------
extern "C" void kernel_launch(void* const* d_in, const int* in_sizes, int n_in,
                              void* d_out, int out_size, void* d_ws, size_t ws_size,
                              hipStream_t stream) {
  const float* x      = (const float*)d_in[0];
  const float* w_qkv  = (const float*)d_in[1];
  const float* b_qkv  = (const float*)d_in[2];
  const float* w_qup  = (const float*)d_in[3];
  const float* b_qup  = (const float*)d_in[4];
  const float* w_kup  = (const float*)d_in[5];
  const float* b_kup  = (const float*)d_in[6];
  const float* w_vup  = (const float*)d_in[7];
  const float* b_vup  = (const float*)d_in[8];
  const float* w_qpos = (const float*)d_in[9];
  const float* b_qpos = (const float*)d_in[10];
  const float* w_kpos = (const float*)d_in[11];
  const float* b_kpos = (const float*)d_in[12];
  const float* w_o    = (const float*)d_in[13];
  const float* b_o    = (const float*)d_in[14];
  (void)in_sizes; (void)n_in; (void)out_size; (void)ws_size;

  char* ws = (char*)d_ws;
  size_t off = 0;
  auto alloc = [&](size_t bytes) -> char* {
    char* p = ws + off;
    off += (bytes + 255) & ~(size_t)255;
    return p;
  };

  unsigned short* wB1    = (unsigned short*)alloc(8388608);   // [2048,2048] (rows 1600+ zero)
  unsigned short* wB2q   = (unsigned short*)alloc(3145728);   // [3072,512]
  unsigned short* wB2k   = (unsigned short*)alloc(2097152);   // [2048,512]
  unsigned short* wB2v   = (unsigned short*)alloc(2097152);   // [2048,512]
  unsigned short* wBo    = (unsigned short*)alloc(8388608);   // [2048,2048]
  float*          bias1  = (float*)alloc(2048 * 4);
  float*          bias2q = (float*)alloc(3072 * 4);
  float*          costab = (float*)alloc(262144);
  float*          sintab = (float*)alloc(262144);
  unsigned short* latext = (unsigned short*)alloc(16777216);  // [4096,2048]
  unsigned short* tmp_q  = (unsigned short*)alloc(25165824);  // [4096,3072]
  unsigned short* tmp_k  = (unsigned short*)alloc(16777216);  // [4096,2048]
  unsigned short* vTbuf  = (unsigned short*)alloc(16777216);  // [32,128,2048]
  unsigned short* posqr  = (unsigned short*)alloc(8388608);   // [4096,1024]
  unsigned short* poskr  = (unsigned short*)alloc(524288);    // [4096,64]
  unsigned short* Opart  = (unsigned short*)alloc(41943040);  // [2560][64][128] bf16
  float*          mlbuf  = (float*)alloc(1310720);            // [2560][64][2]
  int*            counter= (int*)alloc(256);
  unsigned short* attnb  = (unsigned short*)alloc(16777216);  // [4096,2048] bf16

  // 1. fused prep: rope tables, biases, pad, counter reset, 7 weight transposes
  prep_all_kernel<<<11392, 256, 0, stream>>>(b_qkv, b_kpos, b_qup, b_qpos,
                                             bias1, bias2q, costab, sintab, wB1,
                                             w_qkv, w_kpos, w_qup, w_qpos, w_kup,
                                             w_vup, w_o, wB2q, wB2k, wB2v, wBo,
                                             counter);
  // 2. GEMM1 (fp32 A direct): latext[4096,2048] = x @ wB1^T + bias1 (cols 1664+ dead)
  gemm_a32_kernel<<<512, 256, 0, stream>>>(x, 2048, wB1, 2048,
                                           latext, 2048, bias1, 2048, 16);
  // 3. fused up-projections (q-up | k-up | v-up^T), K=512, one dispatch
  gemm_up3_kernel<<<1792, 256, 0, stream>>>(latext, wB2q, wB2k, wB2v,
                                            tmp_q, tmp_k, vTbuf,
                                            bias2q, b_kup, b_vup);
  // 4. rope
  rope_kernel<<<2176, 256, 0, stream>>>(tmp_q, latext, costab, sintab, posqr, poskr);
  // 5. flash attention (KVBLK=32, grid 1280, conflict-free V layout)
  flash_kernel<<<1280, 256, 0, stream>>>(tmp_q, tmp_k, posqr, poskr, vTbuf,
                                         attnb, Opart, mlbuf, counter);
  // 6. merge partials (qt>=8) -> attnb
  merge_kernel<<<768, 256, 0, stream>>>(Opart, mlbuf, attnb);
  // 7. output projection (fp32 out + b_o)
  gemm_bt_kernel<1><<<512, 256, 0, stream>>>(attnb, 2048, wBo, 2048,
                                             d_out, 2048, b_o, 2048, 16);
}

// Round 18
// 265.037 us; speedup vs baseline: 1.0885x; 1.0196x over previous
//
#include <hip/hip_runtime.h>
#include <cstdint>
#include <cstddef>

// ---------- types ----------
typedef __bf16 bf16x8 __attribute__((ext_vector_type(8)));
typedef float  f32x4  __attribute__((ext_vector_type(4)));
typedef unsigned short us8 __attribute__((ext_vector_type(8)));
typedef unsigned short us4 __attribute__((ext_vector_type(4)));

__device__ __forceinline__ unsigned short f2bf(float f) {
  union { float f; unsigned u; } v; v.f = f;
  unsigned r = v.u + 0x7FFFu + ((v.u >> 16) & 1u);
  return (unsigned short)(r >> 16);
}
__device__ __forceinline__ float b2f(unsigned short h) {
  union { unsigned u; float f; } v; v.u = ((unsigned)h) << 16;
  return v.f;
}
__device__ __forceinline__ f32x4 mfma16(bf16x8 a, bf16x8 b, f32x4 c) {
  return __builtin_amdgcn_mfma_f32_16x16x32_bf16(a, b, c, 0, 0, 0);
}
// async global->LDS, 16B per lane; lds dest wave-uniform (HW writes base + lane*16)
__device__ __forceinline__ void gl_lds16(const unsigned short* g, unsigned short* l) {
  __builtin_amdgcn_global_load_lds(
      (const __attribute__((address_space(1))) void*)g,
      (__attribute__((address_space(3))) void*)l, 16, 0, 0);
}

// ---------- fused prep: rope tables + biases + pad + counters + 7 weight transposes ----------
__global__ void prep_all_kernel(const float* __restrict__ b_qkv,
                                const float* __restrict__ b_kpos,
                                const float* __restrict__ b_qup,
                                const float* __restrict__ b_qpos,
                                float* __restrict__ bias1,
                                float* __restrict__ bias2q,
                                float* __restrict__ costab,
                                float* __restrict__ sintab,
                                unsigned short* __restrict__ wB1,
                                const float* __restrict__ w_qkv,
                                const float* __restrict__ w_kpos,
                                const float* __restrict__ w_qup,
                                const float* __restrict__ w_qpos,
                                const float* __restrict__ w_kup,
                                const float* __restrict__ w_vup,
                                const float* __restrict__ w_o,
                                unsigned short* __restrict__ wB2q,
                                unsigned short* __restrict__ wB2k,
                                unsigned short* __restrict__ wB2v,
                                unsigned short* __restrict__ wBo,
                                int* __restrict__ counters) {
  __shared__ float tile[32][33];
  int blk = blockIdx.x;
  if (blk < 512) {
    int i = blk * 256 + threadIdx.x;   // covers 131072
    if (i < 65536) {                   // 2048 x 32 rope tables
      int s = i >> 5, f = i & 31;
      float inv = powf(50000.0f, -(float)f / 32.0f);
      float a = (float)s * inv;
      costab[i] = cosf(a);
      sintab[i] = sinf(a);
    }
    if (i < 2048) bias1[i] = (i < 1536) ? b_qkv[i] : (i < 1600 ? b_kpos[i - 1536] : 0.0f);
    if (i < 3072) bias2q[i] = (i < 2048) ? b_qup[i] : b_qpos[i - 2048];
    for (int jj = 0; jj < 7; ++jj)
      wB1[(size_t)1600 * 2048 + (size_t)jj * 131072 + i] = 0;
    if (i < 64) counters[i] = 0;       // flash steal counter reset
    return;
  }
  const float* in;
  unsigned short* out;
  int ldin, ldo, nx, j;
  if (blk < 3584)      { j = blk - 512;  in = w_qkv;  ldin = 1536; out = wB1;                        ldo = 2048; nx = 48; }
  else if (blk < 3712) { j = blk - 3584; in = w_kpos; ldin = 64;   out = wB1 + (size_t)1536 * 2048;  ldo = 2048; nx = 2;  }
  else if (blk < 4736) { j = blk - 3712; in = w_qup;  ldin = 2048; out = wB2q;                       ldo = 512;  nx = 64; }
  else if (blk < 5248) { j = blk - 4736; in = w_qpos; ldin = 1024; out = wB2q + (size_t)2048 * 512;  ldo = 512;  nx = 32; }
  else if (blk < 6272) { j = blk - 5248; in = w_kup;  ldin = 2048; out = wB2k;                       ldo = 512;  nx = 64; }
  else if (blk < 7296) { j = blk - 6272; in = w_vup;  ldin = 2048; out = wB2v;                       ldo = 512;  nx = 64; }
  else                 { j = blk - 7296; in = w_o;    ldin = 2048; out = wBo;                        ldo = 2048; nx = 64; }
  int c0 = (j % nx) * 32, r0 = (j / nx) * 32;
  int tx = threadIdx.x & 31, ty = threadIdx.x >> 5;
  for (int jj = 0; jj < 4; ++jj)
    tile[ty + jj * 8][tx] = in[(size_t)(r0 + ty + jj * 8) * ldin + c0 + tx];
  __syncthreads();
  for (int jj = 0; jj < 4; ++jj)
    out[(size_t)(c0 + ty + jj * 8) * ldo + r0 + tx] = f2bf(tile[tx][ty + jj * 8]);
}

// ---------- XCD-aware bijective block remap over a local range ----------
__device__ __forceinline__ void xcd_decode_n(int lbid, int nwg, int nx, int& bx, int& by) {
  int cpx = nwg >> 3;
  int wg = (lbid & 7) * cpx + (lbid >> 3);
  bx = wg % nx;
  by = wg / nx;
}
__device__ __forceinline__ void xcd_decode(int nx, int& bx, int& by) {
  xcd_decode_n(blockIdx.x, gridDim.x, nx, bx, by);
}

// ---------- shared GEMM body: C[M,N] = A[M,K]*Bt[N,K]^T + bias ----------
// mode: 0 = bf16 row-major, 1 = f32 row-major, 2 = bf16 transposed (vT epilogue),
//       3 = rope epilogue -> posqr[row][bcol-2048 + ...] (Cout = posqr, needs ct/st).
__device__ __forceinline__
void gemm_body(unsigned short* smem,
               const unsigned short* __restrict__ A, int lda,
               const unsigned short* __restrict__ Bt, int ldb,
               void* __restrict__ Cout, int ldc,
               const float* __restrict__ bias, int K,
               long brow, long bcol, int mode,
               const float* __restrict__ ct, const float* __restrict__ st) {
  int tid = threadIdx.x;
  int wave = tid >> 6, lane = tid & 63;
  int g = lane >> 4, r = lane & 15;
  int wr = wave >> 1, wc = wave & 1;

  int srowl = lane >> 3;
  int sw = ((lane & 7) ^ (srowl & 7)) * 8;
  const unsigned short* Abase = A + (brow + wave * 32 + srowl) * (long)lda + sw;
  const unsigned short* Bbase = Bt + (bcol + wave * 32 + srowl) * (long)ldb + sw;

  f32x4 acc[4][4];
  for (int mi = 0; mi < 4; ++mi)
    for (int ni = 0; ni < 4; ++ni)
      acc[mi][ni] = f32x4{0.f, 0.f, 0.f, 0.f};

  auto stage = [&](int buf, int k0) {
    unsigned short* ab = smem + buf * 16384;
    unsigned short* bb = ab + 8192;
    for (int c = 0; c < 4; ++c) {
      gl_lds16(Abase + (size_t)c * 8 * lda + k0, ab + (wave * 32 + c * 8) * 64);
      gl_lds16(Bbase + (size_t)c * 8 * ldb + k0, bb + (wave * 32 + c * 8) * 64);
    }
  };

  int rx = (r & 7) << 4;
  int nt = K >> 6;

  stage(0, 0);
  for (int t = 0; t < nt; ++t) {
    if (t + 1 < nt) {
      stage((t + 1) & 1, (t + 1) << 6);
      asm volatile("s_waitcnt vmcnt(8)" ::: "memory");
    } else {
      asm volatile("s_waitcnt vmcnt(0)" ::: "memory");
    }
    __builtin_amdgcn_sched_barrier(0);
    __builtin_amdgcn_s_barrier();
    __builtin_amdgcn_sched_barrier(0);
    const char* Ab = (const char*)(smem + (t & 1) * 16384);
    const char* Bb = Ab + 16384;
    for (int kk = 0; kk < 2; ++kk) {
      bf16x8 af[4], bfv[4];
      for (int mi = 0; mi < 4; ++mi)
        af[mi] = *(const bf16x8*)(Ab + (size_t)(wr * 64 + mi * 16 + r) * 128 +
                                  ((kk * 64 + g * 16) ^ rx));
      for (int ni = 0; ni < 4; ++ni)
        bfv[ni] = *(const bf16x8*)(Bb + (size_t)(wc * 64 + ni * 16 + r) * 128 +
                                   ((kk * 64 + g * 16) ^ rx));
      for (int mi = 0; mi < 4; ++mi)
        for (int ni = 0; ni < 4; ++ni)
          acc[mi][ni] = mfma16(af[mi], bfv[ni], acc[mi][ni]);
    }
    __builtin_amdgcn_sched_barrier(0);
    __builtin_amdgcn_s_barrier();
  }

  if (mode == 2) {
    // transposed epilogue -> vT[bh][d][s]; smem reused as [128][136] scratch
    for (int mi = 0; mi < 4; ++mi)
      for (int ni = 0; ni < 4; ++ni) {
        int col = wc * 64 + ni * 16 + r;
        float bv = bias[bcol + col];
        int rowb = wr * 64 + mi * 16 + g * 4;
        for (int i = 0; i < 4; ++i)
          smem[col * 136 + rowb + i] = f2bf(acc[mi][ni][i] + bv);
      }
    __syncthreads();
    int col = tid >> 1, half = tid & 1;
    int bh = (int)(brow >> 11) * 16 + (int)(bcol >> 7);
    unsigned short* outp = (unsigned short*)Cout +
                           ((size_t)bh * 128 + col) * 2048 + (brow & 2047);
    for (int j = 0; j < 8; ++j) {
      int row0 = half * 64 + j * 8;
      *(us8*)(outp + row0) = *(const us8*)&smem[col * 136 + row0];
    }
    return;
  }

  if (mode == 3) {
    // rope epilogue: pairs ni <-> ni^2 are register-local; write posqr only.
    float bv[4];
    for (int ni = 0; ni < 4; ++ni)
      bv[ni] = bias[bcol + wc * 64 + ni * 16 + r];
    unsigned short* outp = (unsigned short*)Cout;   // posqr [4096][1024]
    long cbase = bcol - 2048 + wc * 64;
    for (int mi = 0; mi < 4; ++mi)
      for (int i = 0; i < 4; ++i) {
        long row = brow + wr * 64 + mi * 16 + g * 4 + i;
        int s = (int)(row & 2047);
        float c0 = ct[s * 32 + r],      sn0 = st[s * 32 + r];
        float c1 = ct[s * 32 + 16 + r], sn1 = st[s * 32 + 16 + r];
        float v0 = acc[mi][0][i] + bv[0];
        float v1 = acc[mi][1][i] + bv[1];
        float v2 = acc[mi][2][i] + bv[2];
        float v3 = acc[mi][3][i] + bv[3];
        size_t base = (size_t)row * 1024 + cbase;
        outp[base + r]      = f2bf(v0 * c0 - v2 * sn0);
        outp[base + 16 + r] = f2bf(v1 * c1 - v3 * sn1);
        outp[base + 32 + r] = f2bf(v2 * c0 + v0 * sn0);
        outp[base + 48 + r] = f2bf(v3 * c1 + v1 * sn1);
      }
    return;
  }

  for (int mi = 0; mi < 4; ++mi)
    for (int ni = 0; ni < 4; ++ni) {
      long col = bcol + wc * 64 + ni * 16 + r;
      float bv = bias ? bias[col] : 0.0f;
      long rowb = brow + wr * 64 + mi * 16 + g * 4;
      for (int i = 0; i < 4; ++i) {
        float v = acc[mi][ni][i] + bv;
        if (mode == 1)
          ((float*)Cout)[(rowb + i) * (long)ldc + col] = v;
        else
          ((unsigned short*)Cout)[(rowb + i) * (long)ldc + col] = f2bf(v);
      }
    }
}

// ---------- standalone GEMM (o-proj) ----------
template <int OUT_MODE>
__global__ __launch_bounds__(256, 2)
void gemm_bt_kernel(const unsigned short* __restrict__ A, int lda,
                    const unsigned short* __restrict__ Bt, int ldb,
                    void* __restrict__ Cout, int ldc,
                    const float* __restrict__ bias, int K, int nx) {
  __shared__ unsigned short smem[32768];
  int bx, by;
  xcd_decode(nx, bx, by);
  gemm_body(smem, A, lda, Bt, ldb, Cout, ldc, bias, K,
            (long)by * 128, (long)bx * 128, OUT_MODE, nullptr, nullptr);
}

// ---------- fused up-projections: q-up+rope (768) | k-up (512) | v-up^T (512) ----------
__global__ __launch_bounds__(256, 2)
void gemm_up3_kernel(const unsigned short* __restrict__ latext,
                     const unsigned short* __restrict__ wB2q,
                     const unsigned short* __restrict__ wB2k,
                     const unsigned short* __restrict__ wB2v,
                     unsigned short* __restrict__ tmp_q,
                     unsigned short* __restrict__ tmp_k,
                     unsigned short* __restrict__ vTbuf,
                     unsigned short* __restrict__ posqr,
                     const float* __restrict__ bias2q,
                     const float* __restrict__ b_kup,
                     const float* __restrict__ b_vup,
                     const float* __restrict__ costab,
                     const float* __restrict__ sintab) {
  __shared__ unsigned short smem[32768];
  int bid = blockIdx.x;
  const unsigned short* A;
  const unsigned short* Bt;
  void* C;
  const float* bias;
  int ldc, nx, mode, lbid, nwg;
  if (bid < 768)       { lbid = bid;        nwg = 768; nx = 24; A = latext;        Bt = wB2q; bias = bias2q; ldc = 2048; }
  else if (bid < 1280) { lbid = bid - 768;  nwg = 512; nx = 16; A = latext + 512;  Bt = wB2k; C = tmp_k; ldc = 2048; bias = b_kup; mode = 0; }
  else                 { lbid = bid - 1280; nwg = 512; nx = 16; A = latext + 1024; Bt = wB2v; C = vTbuf; ldc = 2048; bias = b_vup; mode = 2; }
  int bx, by;
  xcd_decode_n(lbid, nwg, nx, bx, by);
  if (bid < 768) {
    if (bx >= 16) { C = posqr; mode = 3; }   // pos cols 2048+: rope -> posqr
    else          { C = tmp_q; mode = 0; }   // nope cols: tmp_q [4096][2048]
  }
  gemm_body(smem, A, 2048, Bt, 512, C, ldc, bias, 512,
            (long)by * 128, (long)bx * 128, mode, costab, sintab);
}

// ---------- GEMM1: A fp32 (x), reg-staged bf16 convert; tile bx==12 ropes pos_k ----------
__global__ __launch_bounds__(256, 2)
void gemm_a32_kernel(const float* __restrict__ A, int lda,
                     const unsigned short* __restrict__ Bt, int ldb,
                     unsigned short* __restrict__ Cout, int ldc,
                     const float* __restrict__ bias, int K, int nx,
                     unsigned short* __restrict__ poskr,
                     const float* __restrict__ costab,
                     const float* __restrict__ sintab) {
  __shared__ unsigned short smem[32768];   // A bufs [0,16384), B bufs [16384,32768)
  int tid = threadIdx.x;
  int wave = tid >> 6, lane = tid & 63;
  int g = lane >> 4, r = lane & 15;
  int wr = wave >> 1, wc = wave & 1;
  int bx, by;
  xcd_decode(nx, bx, by);
  long brow = (long)by * 128, bcol = (long)bx * 128;

  int f4c = tid & 15, row0 = tid >> 4;
  int ablk = f4c >> 1, asub = (f4c & 1) * 8;
  const float4* Ag = (const float4*)(A + (brow + row0) * (size_t)lda) + f4c;

  int srowl = lane >> 3;
  int sw = ((lane & 7) ^ (srowl & 7)) * 8;
  const unsigned short* Bbase = Bt + (bcol + wave * 32 + srowl) * (long)ldb + sw;

  f32x4 acc[4][4];
  for (int mi = 0; mi < 4; ++mi)
    for (int ni = 0; ni < 4; ++ni)
      acc[mi][ni] = f32x4{0.f, 0.f, 0.f, 0.f};

  auto stage_b = [&](int buf, int k0) {
    unsigned short* bb = smem + 16384 + buf * 8192;
    for (int c = 0; c < 4; ++c)
      gl_lds16(Bbase + (size_t)c * 8 * ldb + k0, bb + (wave * 32 + c * 8) * 64);
  };

  int rx = (r & 7) << 4;
  int nt = K >> 6;

  float4 areg[8];
#pragma unroll
  for (int s = 0; s < 8; ++s) areg[s] = Ag[(size_t)s * 8192];
  stage_b(0, 0);

  for (int t = 0; t < nt; ++t) {
    char* alds = (char*)(smem + (t & 1) * 8192);
#pragma unroll
    for (int s = 0; s < 8; ++s) {
      us4 hv;
      hv[0] = f2bf(areg[s].x); hv[1] = f2bf(areg[s].y);
      hv[2] = f2bf(areg[s].z); hv[3] = f2bf(areg[s].w);
      int row = row0 + s * 16;
      *(us4*)(alds + row * 128 + ((ablk ^ (row & 7)) << 4) + asub) = hv;
    }
    asm volatile("s_waitcnt vmcnt(0)" ::: "memory");   // B(t) landed
    asm volatile("s_waitcnt lgkmcnt(0)" ::: "memory"); // A ds_writes committed
    __builtin_amdgcn_sched_barrier(0);
    __builtin_amdgcn_s_barrier();
    __builtin_amdgcn_sched_barrier(0);
    if (t + 1 < nt) {
      int k1 = (t + 1) << 6;
#pragma unroll
      for (int s = 0; s < 8; ++s) areg[s] = Ag[(size_t)s * 8192 + (k1 >> 2)];
      stage_b((t + 1) & 1, k1);
    }
    const char* Ab = (const char*)(smem + (t & 1) * 8192);
    const char* Bb = (const char*)(smem + 16384 + (t & 1) * 8192);
    for (int kk = 0; kk < 2; ++kk) {
      bf16x8 af[4], bfv[4];
      for (int mi = 0; mi < 4; ++mi)
        af[mi] = *(const bf16x8*)(Ab + (size_t)(wr * 64 + mi * 16 + r) * 128 +
                                  ((kk * 64 + g * 16) ^ rx));
      for (int ni = 0; ni < 4; ++ni)
        bfv[ni] = *(const bf16x8*)(Bb + (size_t)(wc * 64 + ni * 16 + r) * 128 +
                                   ((kk * 64 + g * 16) ^ rx));
      for (int mi = 0; mi < 4; ++mi)
        for (int ni = 0; ni < 4; ++ni)
          acc[mi][ni] = mfma16(af[mi], bfv[ni], acc[mi][ni]);
    }
    __builtin_amdgcn_sched_barrier(0);
    __builtin_amdgcn_s_barrier();
  }

  if (bx == 12) {
    // cols 1536..1663: wc==0 waves rope pos_k -> poskr; wc==1 (pad) store nothing.
    if (wc == 0) {
      float bv[4];
      for (int ni = 0; ni < 4; ++ni)
        bv[ni] = bias[1536 + ni * 16 + r];
      for (int mi = 0; mi < 4; ++mi)
        for (int i = 0; i < 4; ++i) {
          long row = brow + wr * 64 + mi * 16 + g * 4 + i;
          int s = (int)(row & 2047);
          float c0 = costab[s * 32 + r],      sn0 = sintab[s * 32 + r];
          float c1 = costab[s * 32 + 16 + r], sn1 = sintab[s * 32 + 16 + r];
          float v0 = acc[mi][0][i] + bv[0];
          float v1 = acc[mi][1][i] + bv[1];
          float v2 = acc[mi][2][i] + bv[2];
          float v3 = acc[mi][3][i] + bv[3];
          size_t base = (size_t)row * 64;
          poskr[base + r]      = f2bf(v0 * c0 - v2 * sn0);
          poskr[base + 16 + r] = f2bf(v1 * c1 - v3 * sn1);
          poskr[base + 32 + r] = f2bf(v2 * c0 + v0 * sn0);
          poskr[base + 48 + r] = f2bf(v3 * c1 + v1 * sn1);
        }
    }
    return;
  }

  for (int mi = 0; mi < 4; ++mi)
    for (int ni = 0; ni < 4; ++ni) {
      long col = bcol + wc * 64 + ni * 16 + r;
      float bv = bias[col];
      long rowb = brow + wr * 64 + mi * 16 + g * 4;
      for (int i = 0; i < 4; ++i)
        Cout[(rowb + i) * (long)ldc + col] = f2bf(acc[mi][ni][i] + bv);
    }
}

// ---------- task decode: 2560 tasks (QBLK=64, <=16 chunks/seg), longest-first ----------
__device__ __forceinline__ void task_decode(int t, int& qt, int& seg, int& bh) {
  if (t < 1024) {
    qt = 31 - (t >> 7); int rem = t & 127; seg = rem >> 5; bh = rem & 31;
  } else if (t < 1792) {
    int t2 = t - 1024; int qi = t2 / 96; int rem = t2 - qi * 96;
    qt = 23 - qi; seg = rem >> 5; bh = rem & 31;
  } else if (t < 2304) {
    int t3 = t - 1792; qt = 15 - (t3 >> 6); int rem = t3 & 63; seg = rem >> 5; bh = rem & 31;
  } else {
    int t4 = t - 2304; qt = 7 - (t4 >> 5); seg = 0; bh = t4 & 31;
  }
}
__device__ __forceinline__ int task_slot(int qt, int seg, int bh) {
  if (qt >= 24) return (31 - qt) * 128 + seg * 32 + bh;
  if (qt >= 16) return 1024 + (23 - qt) * 96 + seg * 32 + bh;
  return 1792 + (15 - qt) * 64 + seg * 32 + bh;
}

// ---------- persistent split-KV causal flash attention (R16, conflict-free V) ----------
__global__ __launch_bounds__(256, 2)
void flash_kernel(const unsigned short* __restrict__ tmp_q,
                  const unsigned short* __restrict__ tmp_k,
                  const unsigned short* __restrict__ posqr,
                  const unsigned short* __restrict__ poskr,
                  const unsigned short* __restrict__ vT,
                  unsigned short* __restrict__ ob,
                  unsigned short* __restrict__ Opart,
                  float* __restrict__ mlbuf,
                  int* __restrict__ counter) {
  const int S = 2048;
  int tid = threadIdx.x, wave = tid >> 6, lane = tid & 63;
  int g = lane >> 4, r = lane & 15;
  const float sl2 = 1.44269504f / 13.8564064605510183f;  // log2e / sqrt(192)
  const float DEFER = 96.0f;

  __shared__ unsigned short Klds[32 * 192];   // 32 rows x 384B, blk16 ^= row&7
  __shared__ unsigned short Vlds[64 * 64];    // 64 rows x 128B: d-rows d,(d+64); blk ^= d&7
  __shared__ unsigned short Plds[4][16][40];
  __shared__ int s_tile;
  char* Kb = (char*)Klds;
  char* Vb = (char*)Vlds;
  int rx7 = (r & 7) << 4;

  us8 onesu;
  for (int e = 0; e < 8; ++e) onesu[e] = 0x3F80;
  bf16x8 ones = *(const bf16x8*)&onesu;

  int kn_row[2], kn_seg[2];
  for (int j = 0; j < 2; ++j) {
    int slot = j * 256 + tid;
    kn_row[j] = slot >> 4;
    kn_seg[j] = slot & 15;
  }
  int kr_row = tid >> 3, kr_seg = tid & 7;
  int v_row[2], v_seg[2];
  for (int j = 0; j < 2; ++j) {
    int slot = j * 256 + tid;
    v_row[j] = slot >> 2;
    v_seg[j] = slot & 3;
  }

  for (;;) {
    if (tid == 0) s_tile = atomicAdd(counter, 1);
    __syncthreads();
    int t = s_tile;
    if (t >= 2560) return;
    int qt, seg, bh;
    task_decode(t, qt, seg, bh);
    int b = bh >> 4, h = bh & 15;
    int qbase = qt * 64;
    int cbeg = seg * 16;
    int cend = min(cbeg + 16, 2 * (qt + 1));
    size_t rb = (size_t)b * 2048;

    const unsigned short* kpn = tmp_k + rb * 2048 + h * 128;
    const unsigned short* kpr = poskr + rb * 64;
    const unsigned short* vp = vT + (size_t)bh * 128 * S;

    bf16x8 qf[6];
    {
      size_t qrowA = rb + qbase + wave * 16 + r;
      const unsigned short* qn = tmp_q + qrowA * 2048 + h * 128 + g * 8;
      for (int c = 0; c < 4; ++c) qf[c] = *(const bf16x8*)(qn + c * 32);
      const unsigned short* qr_ = posqr + qrowA * 1024 + h * 64 + g * 8;
      qf[4] = *(const bf16x8*)(qr_);
      qf[5] = *(const bf16x8*)(qr_ + 32);
    }

    f32x4 acc[8];
    for (int d = 0; d < 8; ++d) acc[d] = f32x4{0.f, 0.f, 0.f, 0.f};
    f32x4 lacc = {0.f, 0.f, 0.f, 0.f};
    float m_r[4];
    for (int i = 0; i < 4; ++i) m_r[i] = -3.0e38f;

    us8 kreg[2], krope, vreg[2];
    {
      int kv0 = cbeg * 32;
      for (int j = 0; j < 2; ++j)
        kreg[j] = *(const us8*)(kpn + (size_t)(kv0 + kn_row[j]) * 2048 + kn_seg[j] * 8);
      krope = *(const us8*)(kpr + (size_t)(kv0 + kr_row) * 64 + kr_seg * 8);
      for (int j = 0; j < 2; ++j)
        vreg[j] = *(const us8*)(vp + (size_t)v_row[j] * S + kv0 + v_seg[j] * 8);
    }

    for (int ch = cbeg; ch < cend; ++ch) {
      for (int j = 0; j < 2; ++j)
        *(us8*)(Kb + (size_t)kn_row[j] * 384 +
                ((kn_seg[j] ^ (kn_row[j] & 7)) << 4)) = kreg[j];
      *(us8*)(Kb + (size_t)kr_row * 384 +
              (((16 + kr_seg) ^ (kr_row & 7)) << 4)) = krope;
      for (int j = 0; j < 2; ++j) {
        int d = v_row[j];
        *(us8*)(Vb + (size_t)(d & 63) * 128 +
                ((((d >> 6) * 4 + v_seg[j]) ^ (d & 7)) << 4)) = vreg[j];
      }
      asm volatile("s_waitcnt lgkmcnt(0)" ::: "memory");
      __builtin_amdgcn_sched_barrier(0);
      __builtin_amdgcn_s_barrier();
      __builtin_amdgcn_sched_barrier(0);
      if (ch + 1 < cend) {
        int kv1 = (ch + 1) * 32;
        for (int j = 0; j < 2; ++j)
          kreg[j] = *(const us8*)(kpn + (size_t)(kv1 + kn_row[j]) * 2048 + kn_seg[j] * 8);
        krope = *(const us8*)(kpr + (size_t)(kv1 + kr_row) * 64 + kr_seg * 8);
        for (int j = 0; j < 2; ++j)
          vreg[j] = *(const us8*)(vp + (size_t)v_row[j] * S + kv1 + v_seg[j] * 8);
      }
      int kv0 = ch * 32;

      f32x4 sc0 = {0.f, 0.f, 0.f, 0.f}, sc1 = {0.f, 0.f, 0.f, 0.f};
      __builtin_amdgcn_s_setprio(1);
      for (int c = 0; c < 6; ++c) {
        bf16x8 kf0 = *(const bf16x8*)(Kb + (size_t)r * 384 + (((c * 4 + g) << 4) ^ rx7));
        sc0 = mfma16(qf[c], kf0, sc0);
      }
      for (int c = 0; c < 6; ++c) {
        bf16x8 kf1 = *(const bf16x8*)(Kb + (size_t)(16 + r) * 384 + (((c * 4 + g) << 4) ^ rx7));
        sc1 = mfma16(qf[c], kf1, sc1);
      }
      __builtin_amdgcn_s_setprio(0);

      int qi_min = qbase + wave * 16;
      if (kv0 + 31 > qi_min) {
        int kj0 = kv0 + r, kj1 = kv0 + 16 + r;
        int qi0 = qi_min + g * 4;
        for (int i = 0; i < 4; ++i) {
          if (kj0 > qi0 + i) sc0[i] = -1e30f;
          if (kj1 > qi0 + i) sc1[i] = -1e30f;
        }
      }

      float tl[4];
      bool ok = true;
      for (int i = 0; i < 4; ++i) {
        tl[i] = fmaxf(sc0[i], sc1[i]);
        ok = ok && (tl[i] - m_r[i] <= DEFER);
      }
      if (!__all(ok)) {
        for (int i = 0; i < 4; ++i) {
          float tm = tl[i];
          for (int off = 1; off < 16; off <<= 1) tm = fmaxf(tm, __shfl_xor(tm, off, 64));
          float mnew = fmaxf(m_r[i], tm);
          float corr = exp2f((m_r[i] - mnew) * sl2);
          lacc[i] *= corr;
          for (int d = 0; d < 8; ++d) acc[d][i] *= corr;
          m_r[i] = mnew;
        }
      }
      float p0[4], p1[4];
      for (int i = 0; i < 4; ++i) {
        p0[i] = exp2f((sc0[i] - m_r[i]) * sl2);
        p1[i] = exp2f((sc1[i] - m_r[i]) * sl2);
      }

      for (int i = 0; i < 4; ++i) {
        Plds[wave][g * 4 + i][r] = f2bf(p0[i]);
        Plds[wave][g * 4 + i][16 + r] = f2bf(p1[i]);
      }
      bf16x8 pa = *(const bf16x8*)&Plds[wave][r][g * 8];
      __builtin_amdgcn_s_setprio(1);
      lacc = mfma16(pa, ones, lacc);
      for (int dt = 0; dt < 8; ++dt) {
        bf16x8 vf = *(const bf16x8*)(Vb + (size_t)((dt & 3) * 16 + r) * 128 +
                                     ((((dt >> 2) * 4 + g) << 4) ^ rx7));
        acc[dt] = mfma16(pa, vf, acc[dt]);
      }
      __builtin_amdgcn_s_setprio(0);
      __builtin_amdgcn_sched_barrier(0);
      __builtin_amdgcn_s_barrier();
    }

    if (qt <= 7) {
      for (int i = 0; i < 4; ++i) {
        float inv = 1.0f / lacc[i];
        int row = qbase + wave * 16 + g * 4 + i;
        size_t base = (rb + row) * 2048 + h * 128;
        for (int dt = 0; dt < 8; ++dt)
          ob[base + dt * 16 + r] = f2bf(acc[dt][i] * inv);
      }
    } else {
      unsigned short* op = Opart + (size_t)t * 8192;
      for (int i = 0; i < 4; ++i) {
        int row = wave * 16 + g * 4 + i;
        for (int dt = 0; dt < 8; ++dt)
          op[row * 128 + dt * 16 + r] = f2bf(acc[dt][i]);
        if (r == 0) {
          mlbuf[(size_t)t * 128 + row * 2]     = m_r[i];
          mlbuf[(size_t)t * 128 + row * 2 + 1] = lacc[i];
        }
      }
    }
  }
}

// ---------- merge partials (qt>=8) -> attn bf16 [B*S, 2048] ----------
__global__ void merge_kernel(const unsigned short* __restrict__ Opart,
                             const float* __restrict__ mlbuf,
                             unsigned short* __restrict__ ob) {
  int qt = 8 + (blockIdx.x >> 5), bh = blockIdx.x & 31;
  int b = bh >> 4, h = bh & 15;
  int tid = threadIdx.x;
  int row = tid >> 2, c0 = (tid & 3) * 32;
  const float sl2 = 1.44269504f / 13.8564064605510183f;
  int ns = (qt >= 24) ? 4 : (qt >= 16 ? 3 : 2);

  size_t slot[4];
  float m[4], l[4], w[4];
  float M = -3.0e38f;
#pragma unroll
  for (int j = 0; j < 4; ++j) {
    if (j < ns) {
      slot[j] = task_slot(qt, j, bh);
      m[j] = mlbuf[slot[j] * 128 + row * 2];
      l[j] = mlbuf[slot[j] * 128 + row * 2 + 1];
      M = fmaxf(M, m[j]);
    }
  }
  float L = 0.f;
#pragma unroll
  for (int j = 0; j < 4; ++j)
    if (j < ns) { w[j] = exp2f((m[j] - M) * sl2); L += w[j] * l[j]; }
  float invL = 1.f / L;
#pragma unroll
  for (int j = 0; j < 4; ++j) if (j < ns) w[j] *= invL;

  float o[32];
#pragma unroll
  for (int e = 0; e < 32; ++e) o[e] = 0.f;
#pragma unroll
  for (int j = 0; j < 4; ++j) {
    if (j < ns) {
      const unsigned short* pp = Opart + slot[j] * 8192 + row * 128 + c0;
      for (int blk = 0; blk < 4; ++blk) {
        us8 v = *(const us8*)(pp + blk * 8);
        for (int e = 0; e < 8; ++e) o[blk * 8 + e] += w[j] * b2f(v[e]);
      }
    }
  }
  size_t obase = ((size_t)b * 2048 + qt * 64 + row) * 2048 + h * 128 + c0;
  for (int blk = 0; blk < 4; ++blk) {
    us8 st;
    for (int e = 0; e < 8; ++e) st[e] = f2bf(o[blk * 8 + e]);
    *(us8*)(ob + obase + blk * 8) = st;
  }
}

// ---------- launcher ----------
extern "C" void kernel_launch(void* const* d_in, const int* in_sizes, int n_in,
                              void* d_out, int out_size, void* d_ws, size_t ws_size,
                              hipStream_t stream) {
  const float* x      = (const float*)d_in[0];
  const float* w_qkv  = (const float*)d_in[1];
  const float* b_qkv  = (const float*)d_in[2];
  const float* w_qup  = (const float*)d_in[3];
  const float* b_qup  = (const float*)d_in[4];
  const float* w_kup  = (const float*)d_in[5];
  const float* b_kup  = (const float*)d_in[6];
  const float* w_vup  = (const float*)d_in[7];
  const float* b_vup  = (const float*)d_in[8];
  const float* w_qpos = (const float*)d_in[9];
  const float* b_qpos = (const float*)d_in[10];
  const float* w_kpos = (const float*)d_in[11];
  const float* b_kpos = (const float*)d_in[12];
  const float* w_o    = (const float*)d_in[13];
  const float* b_o    = (const float*)d_in[14];
  (void)in_sizes; (void)n_in; (void)out_size; (void)ws_size;

  char* ws = (char*)d_ws;
  size_t off = 0;
  auto alloc = [&](size_t bytes) -> char* {
    char* p = ws + off;
    off += (bytes + 255) & ~(size_t)255;
    return p;
  };

  unsigned short* wB1    = (unsigned short*)alloc(8388608);   // [2048,2048] (rows 1600+ zero)
  unsigned short* wB2q   = (unsigned short*)alloc(3145728);   // [3072,512]
  unsigned short* wB2k   = (unsigned short*)alloc(2097152);   // [2048,512]
  unsigned short* wB2v   = (unsigned short*)alloc(2097152);   // [2048,512]
  unsigned short* wBo    = (unsigned short*)alloc(8388608);   // [2048,2048]
  float*          bias1  = (float*)alloc(2048 * 4);
  float*          bias2q = (float*)alloc(3072 * 4);
  float*          costab = (float*)alloc(262144);
  float*          sintab = (float*)alloc(262144);
  unsigned short* latext = (unsigned short*)alloc(16777216);  // [4096,2048] (cols 1536+ unused)
  unsigned short* tmp_q  = (unsigned short*)alloc(16777216);  // [4096,2048] (nope only)
  unsigned short* tmp_k  = (unsigned short*)alloc(16777216);  // [4096,2048]
  unsigned short* vTbuf  = (unsigned short*)alloc(16777216);  // [32,128,2048]
  unsigned short* posqr  = (unsigned short*)alloc(8388608);   // [4096,1024]
  unsigned short* poskr  = (unsigned short*)alloc(524288);    // [4096,64]
  unsigned short* Opart  = (unsigned short*)alloc(41943040);  // [2560][64][128] bf16
  float*          mlbuf  = (float*)alloc(1310720);            // [2560][64][2]
  int*            counter= (int*)alloc(256);
  unsigned short* attnb  = (unsigned short*)alloc(16777216);  // [4096,2048] bf16

  // 1. fused prep: rope tables, biases, pad, counter reset, 7 weight transposes
  prep_all_kernel<<<11392, 256, 0, stream>>>(b_qkv, b_kpos, b_qup, b_qpos,
                                             bias1, bias2q, costab, sintab, wB1,
                                             w_qkv, w_kpos, w_qup, w_qpos, w_kup,
                                             w_vup, w_o, wB2q, wB2k, wB2v, wBo,
                                             counter);
  // 2. GEMM1 (fp32 A direct, 13 col-tiles): latext cols 0-1535; tile 12 ropes -> poskr
  gemm_a32_kernel<<<416, 256, 0, stream>>>(x, 2048, wB1, 2048,
                                           latext, 2048, bias1, 2048, 13,
                                           poskr, costab, sintab);
  // 3. fused up-projections (q-up nope->tmp_q, q-pos rope->posqr | k-up | v-up^T)
  gemm_up3_kernel<<<1792, 256, 0, stream>>>(latext, wB2q, wB2k, wB2v,
                                            tmp_q, tmp_k, vTbuf, posqr,
                                            bias2q, b_kup, b_vup, costab, sintab);
  // 4. flash attention (KVBLK=32, grid 1280, conflict-free V layout)
  flash_kernel<<<1280, 256, 0, stream>>>(tmp_q, tmp_k, posqr, poskr, vTbuf,
                                         attnb, Opart, mlbuf, counter);
  // 5. merge partials (qt>=8) -> attnb
  merge_kernel<<<768, 256, 0, stream>>>(Opart, mlbuf, attnb);
  // 6. output projection (fp32 out + b_o)
  gemm_bt_kernel<1><<<512, 256, 0, stream>>>(attnb, 2048, wBo, 2048,
                                             d_out, 2048, b_o, 2048, 16);
}